// Round 2
// baseline (372.217 us; speedup 1.0000x reference)
//
#include <hip/hip_runtime.h>

// Problem constants
#define B_    8
#define NA_   4096
#define NAA_  1024
#define NPC_  4096
#define K_    16
#define KNC_  14
#define G_    32
#define DA_   12
#define F_    128
#define D_    128
#define T_    8      // atoms per block in k_atom

// ---------------------------------------------------------------------------
// Kernel 1: per-atom frame + gaussian embedding + y/att/feat
// grid = B*NA/T blocks, 128 threads (thread = output feature), T atoms/block
// ---------------------------------------------------------------------------
__global__ __launch_bounds__(128) void k_atom(
    const float* __restrict__ pc,         // (B,NPC,3)
    const float* __restrict__ mask_atom,  // (B,NA,1)
    const float* __restrict__ attr_table, // (39,12)
    const float* __restrict__ gauss,      // (32,3)
    const float* __restrict__ W_nem,      // (32,12,128)
    const float* __restrict__ W_att,      // (128,128)
    const float* __restrict__ W_feat,     // (128,128)
    const int* __restrict__ frame_idx,    // (B,NA,3)
    const int* __restrict__ attr_idx,     // (B,NA)
    const int* __restrict__ nb_idx,       // (B,NA,16)
    float* __restrict__ att, float* __restrict__ feat, float* __restrict__ mask_y)
{
    const int a0  = blockIdx.x * T_;      // first atom (b*NA + n), T_ | NA_
    const int b   = a0 >> 12;             // NA = 4096
    const int tid = threadIdx.x;

    __shared__ float Rs[T_][3][3];
    __shared__ float cen[T_][3];
    __shared__ float myv[T_];
    __shared__ int   nbs[T_][K_];
    __shared__ float rels[T_][K_][3];
    __shared__ float anb[T_][K_][DA_];
    __shared__ float gs[T_][K_][G_];
    __shared__ float Ms[T_][G_ * DA_];
    __shared__ float ys[T_][F_];

    // ---- phase 1: frames + masks (8 threads), neighbor indices (128 threads)
    if (tid < T_) {
        const int atom = a0 + tid;
        const int fb = atom * 3;
        const int i0 = frame_idx[fb + 0];
        const int i1 = frame_idx[fb + 1];
        const int i2 = frame_idx[fb + 2];
        const float* pcb = pc + (size_t)b * NPC_ * 3;
        float p0x = pcb[i0*3+0], p0y = pcb[i0*3+1], p0z = pcb[i0*3+2];
        float cx  = pcb[i1*3+0], cy  = pcb[i1*3+1], cz  = pcb[i1*3+2];
        float p2x = pcb[i2*3+0], p2y = pcb[i2*3+1], p2z = pcb[i2*3+2];
        float u1x = p2x - cx, u1y = p2y - cy, u1z = p2z - cz;
        float n1 = sqrtf(u1x*u1x + u1y*u1y + u1z*u1z) + 1e-8f;
        u1x /= n1; u1y /= n1; u1z /= n1;
        float vx = p0x - cx, vy = p0y - cy, vz = p0z - cz;
        float dot = vx*u1x + vy*u1y + vz*u1z;
        float u2x = vx - dot*u1x, u2y = vy - dot*u1y, u2z = vz - dot*u1z;
        float n2 = sqrtf(u2x*u2x + u2y*u2y + u2z*u2z) + 1e-8f;
        u2x /= n2; u2y /= n2; u2z /= n2;
        float u3x = u1y*u2z - u1z*u2y;
        float u3y = u1z*u2x - u1x*u2z;
        float u3z = u1x*u2y - u1y*u2x;
        Rs[tid][0][0]=u1x; Rs[tid][0][1]=u1y; Rs[tid][0][2]=u1z;
        Rs[tid][1][0]=u2x; Rs[tid][1][1]=u2y; Rs[tid][1][2]=u2z;
        Rs[tid][2][0]=u3x; Rs[tid][2][1]=u3y; Rs[tid][2][2]=u3z;
        cen[tid][0]=cx; cen[tid][1]=cy; cen[tid][2]=cz;
        const int ai = attr_idx[atom];
        float m = 0.f;
        #pragma unroll
        for (int a = 0; a < DA_; a++)
            if (attr_table[ai*DA_ + a] != 0.f) m = 1.f;
        myv[tid] = mask_atom[atom] * m;
    }
    {   // 128 threads = T_*K_ neighbor indices
        const int t = tid >> 4, k = tid & 15;
        nbs[t][k] = nb_idx[(a0 + t) * K_ + k];
    }
    __syncthreads();

    // ---- phase 2: rel coords (128 threads = T*K)
    {
        const int t = tid >> 4, k = tid & 15;
        const int j  = nbs[t][k];
        const int fj = frame_idx[(b * NA_ + j) * 3 + 1];
        const float* pcb = pc + (size_t)b * NPC_ * 3;
        float dx = pcb[fj*3+0] - cen[t][0];
        float dy = pcb[fj*3+1] - cen[t][1];
        float dz = pcb[fj*3+2] - cen[t][2];
        rels[t][k][0] = Rs[t][0][0]*dx + Rs[t][0][1]*dy + Rs[t][0][2]*dz;
        rels[t][k][1] = Rs[t][1][0]*dx + Rs[t][1][1]*dy + Rs[t][1][2]*dz;
        rels[t][k][2] = Rs[t][2][0]*dx + Rs[t][2][1]*dy + Rs[t][2][2]*dz;
    }
    // neighbor attrs (a*mattr == a: mattr=0 only when the row is all-zero)
    for (int idx = tid; idx < T_ * K_ * DA_; idx += 128) {
        const int t = idx / (K_ * DA_);
        const int r = idx % (K_ * DA_);
        const int k = r / DA_, a = r % DA_;
        const int j  = nbs[t][k];
        const int ai = attr_idx[b * NA_ + j];
        anb[t][k][a] = attr_table[ai * DA_ + a];
    }
    __syncthreads();

    // ---- phase 3: gaussian embedding (T*K*G = 4096 -> 32/thread)
    for (int idx = tid; idx < T_ * K_ * G_; idx += 128) {
        const int t = idx >> 9;          // K*G = 512
        const int r = idx & 511;
        const int k = r >> 5, g = r & 31;
        float dx = rels[t][k][0] - gauss[g*3+0];
        float dy = rels[t][k][1] - gauss[g*3+1];
        float dz = rels[t][k][2] - gauss[g*3+2];
        gs[t][k][g] = expf(-0.5f * (dx*dx + dy*dy + dz*dz));
    }
    __syncthreads();

    // ---- phase 4: M[t][g,a] = sum_k g*anb  (T*G*DA = 3072 -> 24/thread)
    for (int idx = tid; idx < T_ * G_ * DA_; idx += 128) {
        const int t  = idx / (G_ * DA_);
        const int ga = idx % (G_ * DA_);
        const int g = ga / DA_, a = ga % DA_;
        float s = 0.f;
        #pragma unroll
        for (int k = 0; k < K_; k++) s += gs[t][k][g] * anb[t][k][a];
        Ms[t][ga] = s;
    }
    __syncthreads();

    // ---- phase 5: y[t][f] = (1/K)*myv * sum_ga Ms[t][ga]*W_nem[ga][f]
    {
        float acc[T_];
        #pragma unroll
        for (int t = 0; t < T_; t++) acc[t] = 0.f;
        const float* w = W_nem + tid;
        #pragma unroll 4
        for (int ga = 0; ga < G_ * DA_; ga++) {
            const float wv = w[(size_t)ga * F_];
            #pragma unroll
            for (int t = 0; t < T_; t++) acc[t] += Ms[t][ga] * wv;
        }
        #pragma unroll
        for (int t = 0; t < T_; t++)
            ys[t][tid] = acc[t] * (1.f / (float)K_) * myv[t];
    }
    __syncthreads();

    // ---- phase 6: att/feat matvecs, weight loads amortized over T atoms
    {
        float aA[T_], aF[T_];
        #pragma unroll
        for (int t = 0; t < T_; t++) { aA[t] = 0.f; aF[t] = 0.f; }
        #pragma unroll 2
        for (int j = 0; j < F_; j++) {
            const float wa = W_att [j * F_ + tid];
            const float wf = W_feat[j * F_ + tid];
            #pragma unroll
            for (int t = 0; t < T_; t++) {
                const float yv = ys[t][j];
                aA[t] += yv * wa;
                aF[t] += yv * wf;
            }
        }
        #pragma unroll
        for (int t = 0; t < T_; t++) {
            const size_t o = (size_t)(a0 + t) * F_ + tid;
            att[o]  = aA[t] * myv[t];
            feat[o] = aF[t] * myv[t];
        }
        if (tid < T_) mask_y[a0 + tid] = myv[tid];
    }
}

// ---------------------------------------------------------------------------
// Kernel 2: per-AA-row masked/gated softmax pooling
// grid = B*NAA blocks, 128 threads (thread = feature)
// ---------------------------------------------------------------------------
__global__ __launch_bounds__(128) void k_pool(
    const float* __restrict__ att, const float* __restrict__ feat,
    const float* __restrict__ mask_y,
    const float* __restrict__ mask_aa,     // (B,NAA,1)
    const int* __restrict__ seq_idx_atom,  // (B,NA)
    const int* __restrict__ seq_idx_aa,    // (B,NAA)
    const int* __restrict__ aa_nb_idx,     // (B,NAA,14)
    float* __restrict__ pooled)
{
    const int row = blockIdx.x;       // b*NAA + i
    const int b   = row >> 10;        // NAA = 1024
    const int tid = threadIdx.x;

    __shared__ float gateS[KNC_], maskS[KNC_];
    __shared__ int   jS[KNC_];

    if (tid < KNC_) {
        const int j = aa_nb_idx[row * KNC_ + tid];
        jS[tid] = j;
        maskS[tid] = mask_y[b * NA_ + j];
        const int sa = seq_idx_aa[row];
        const int sn = seq_idx_atom[b * NA_ + j];
        gateS[tid] = (sn == sa) ? 1.f : 0.f;
    }
    __syncthreads();

    float av[KNC_], fv[KNC_];
    #pragma unroll
    for (int k = 0; k < KNC_; k++) {
        const size_t o = ((size_t)(b * NA_ + jS[k])) * F_ + tid;
        av[k] = att[o];
        fv[k] = feat[o];
    }
    float m = -1e30f;
    #pragma unroll
    for (int k = 0; k < KNC_; k++) {
        const float l = (maskS[k] > 0.f) ? av[k] : -1e9f;
        av[k] = l;
        m = fmaxf(m, l);
    }
    float s = 0.f;
    #pragma unroll
    for (int k = 0; k < KNC_; k++) { av[k] = expf(av[k] - m); s += av[k]; }
    float tot = 0.f, p = 0.f;
    #pragma unroll
    for (int k = 0; k < KNC_; k++) {
        const float w = av[k] / s * gateS[k] * maskS[k];
        tot += w;
        p   += w * fv[k];
    }
    p = p / (tot + 1e-8f);
    p *= mask_aa[row];
    pooled[(size_t)row * F_ + tid] = p;
}

// ---------------------------------------------------------------------------
// Kernel 3: stats (per-feature sum & sumsq; mask count)
// grid = 64 blocks x 128 threads; block handles 128 rows
// ---------------------------------------------------------------------------
__global__ __launch_bounds__(128) void k_stats(
    const float* __restrict__ pooled,
    const float* __restrict__ mask_aa,
    float* __restrict__ stats)   // [0..127]=S1, [128..255]=S2, [256]=n
{
    const int tid = threadIdx.x;
    const int r0  = blockIdx.x * 128;
    float s1 = 0.f, s2 = 0.f;
    for (int r = 0; r < 128; r++) {
        const float v = pooled[(size_t)(r0 + r) * F_ + tid];
        s1 += v;
        s2 += v * v;
    }
    atomicAdd(&stats[tid], s1);
    atomicAdd(&stats[F_ + tid], s2);
    if (tid == 0) {
        float n = 0.f;
        for (int r = 0; r < 128; r++) n += mask_aa[r0 + r];
        atomicAdd(&stats[2 * F_], n);
    }
}

// ---------------------------------------------------------------------------
// Kernel 4: batchnorm + relu + store; echo mask_aa as output 1
// ---------------------------------------------------------------------------
__global__ __launch_bounds__(256) void k_final(
    const float* __restrict__ pooled,
    const float* __restrict__ stats,
    const float* __restrict__ gamma,
    const float* __restrict__ beta,
    const float* __restrict__ mask_aa,
    float* __restrict__ out)
{
    const int idx = blockIdx.x * 256 + threadIdx.x;   // < B*NAA*D
    const int f   = idx & (D_ - 1);
    const int row = idx >> 7;
    const float n    = stats[2 * F_] + 1e-8f;
    const float mean = stats[f] / n;
    const float var  = stats[F_ + f] / n - mean * mean;
    const float ma   = mask_aa[row];
    float v = gamma[f] * (pooled[idx] - mean) * rsqrtf(var + 1e-5f) + beta[f];
    v = fmaxf(v * ma, 0.f);
    out[idx] = v;
    if (idx < B_ * NAA_) out[B_ * NAA_ * D_ + idx] = mask_aa[idx];
}

// ---------------------------------------------------------------------------
extern "C" void kernel_launch(void* const* d_in, const int* in_sizes, int n_in,
                              void* d_out, int out_size, void* d_ws, size_t ws_size,
                              hipStream_t stream) {
    const float* pc         = (const float*)d_in[0];
    const float* mask_atom  = (const float*)d_in[1];
    const float* mask_aa    = (const float*)d_in[2];
    const float* attr_table = (const float*)d_in[3];
    const float* gauss      = (const float*)d_in[4];
    const float* W_nem      = (const float*)d_in[5];
    const float* W_att      = (const float*)d_in[6];
    const float* W_feat     = (const float*)d_in[7];
    const float* gamma      = (const float*)d_in[8];
    const float* beta       = (const float*)d_in[9];
    const int* frame_idx    = (const int*)d_in[10];
    const int* attr_idx     = (const int*)d_in[11];
    const int* nb_idx       = (const int*)d_in[12];
    const int* seq_idx_atom = (const int*)d_in[13];
    const int* seq_idx_aa   = (const int*)d_in[14];
    const int* aa_nb_idx    = (const int*)d_in[15];

    float* ws     = (float*)d_ws;
    float* att    = ws;                           // B*NA*F   = 4194304
    float* feat   = att    + (size_t)B_*NA_*F_;   // 4194304
    float* masky  = feat   + (size_t)B_*NA_*F_;   // 32768
    float* pooled = masky  + (size_t)B_*NA_;      // 1048576
    float* stats  = pooled + (size_t)B_*NAA_*F_;  // 257

    hipMemsetAsync(stats, 0, 257 * sizeof(float), stream);

    k_atom<<<B_*NA_/T_, 128, 0, stream>>>(pc, mask_atom, attr_table, gauss,
                                          W_nem, W_att, W_feat,
                                          frame_idx, attr_idx, nb_idx,
                                          att, feat, masky);
    k_pool<<<B_*NAA_, 128, 0, stream>>>(att, feat, masky, mask_aa,
                                        seq_idx_atom, seq_idx_aa, aa_nb_idx,
                                        pooled);
    k_stats<<<64, 128, 0, stream>>>(pooled, mask_aa, stats);
    k_final<<<(B_*NAA_*D_) / 256, 256, 0, stream>>>(pooled, stats, gamma, beta,
                                                    mask_aa, (float*)d_out);
}

// Round 3
// 195.448 us; speedup vs baseline: 1.9044x; 1.9044x over previous
//
#include <hip/hip_runtime.h>
#include <hip/hip_bf16.h>

// Problem constants
#define B_    8
#define NA_   4096
#define NAA_  1024
#define NPC_  4096
#define K_    16
#define KNC_  14
#define G_    32
#define DA_   12
#define F_    128
#define D_    128

typedef __attribute__((ext_vector_type(8))) short short8;
typedef __attribute__((ext_vector_type(4))) float floatx4;

__device__ __forceinline__ unsigned short f2bf(float x) {
    __hip_bfloat16 h = __float2bfloat16(x);
    return *reinterpret_cast<unsigned short*>(&h);
}
__device__ __forceinline__ float bf2f(unsigned short u) {
    __hip_bfloat16 h;
    *reinterpret_cast<unsigned short*>(&h) = u;
    return __bfloat162float(h);
}

// ---------------------------------------------------------------------------
// k_prep: transpose weights to bf16.
//   WnT[f][ga] = W_nem[ga][f]          (128 x 384)
//   W2T[n][k]  = n<128 ? W_att[k][n] : W_feat[k][n-128]   (256 x 128)
// ---------------------------------------------------------------------------
__global__ __launch_bounds__(256) void k_prep(
    const float* __restrict__ W_nem, const float* __restrict__ W_att,
    const float* __restrict__ W_feat,
    unsigned short* __restrict__ WnT, unsigned short* __restrict__ W2T)
{
    const int idx = blockIdx.x * 256 + threadIdx.x;   // < 49152 + 32768
    if (idx < 128 * 384) {
        const int f = idx / 384, ga = idx % 384;
        WnT[idx] = f2bf(W_nem[(size_t)ga * F_ + f]);
    } else if (idx < 128 * 384 + 256 * 128) {
        const int j = idx - 128 * 384;
        const int n = j / 128, k = j % 128;
        const float v = (n < 128) ? W_att[(size_t)k * F_ + n]
                                  : W_feat[(size_t)k * F_ + (n - 128)];
        W2T[j] = f2bf(v);
    }
}

// ---------------------------------------------------------------------------
// k_geom: frames + gaussian embedding + M (bf16) + mask_y
// block = 256 threads = 8 atoms x 32 lanes (lane = gaussian g); gs in regs.
// ---------------------------------------------------------------------------
__global__ __launch_bounds__(256) void k_geom(
    const float* __restrict__ pc,         // (B,NPC,3)
    const float* __restrict__ mask_atom,  // (B,NA)
    const float* __restrict__ attr_table, // (39,12)
    const float* __restrict__ gauss,      // (32,3)
    const int* __restrict__ frame_idx,    // (B,NA,3)
    const int* __restrict__ attr_idx,     // (B,NA)
    const int* __restrict__ nb_idx,       // (B,NA,16)
    unsigned int* __restrict__ Mout,      // (32768, 384) bf16, as u32 pairs
    float* __restrict__ mask_y)
{
    const int a0  = blockIdx.x * 8;
    const int b   = a0 >> 12;             // NA = 4096
    const int tid = threadIdx.x;

    __shared__ float Rs[8][9];
    __shared__ float cen[8][3];
    __shared__ float mvs[8];
    __shared__ int   nbs[8][K_];
    __shared__ int   ais[8][K_];
    __shared__ float rel[8][K_][3];
    __shared__ float anb[8][K_][DA_];

    if (tid < 8) {
        const int atom = a0 + tid;
        const int fb = atom * 3;
        const int i0 = frame_idx[fb + 0];
        const int i1 = frame_idx[fb + 1];
        const int i2 = frame_idx[fb + 2];
        const float* pcb = pc + (size_t)b * NPC_ * 3;
        float p0x = pcb[i0*3+0], p0y = pcb[i0*3+1], p0z = pcb[i0*3+2];
        float cx  = pcb[i1*3+0], cy  = pcb[i1*3+1], cz  = pcb[i1*3+2];
        float p2x = pcb[i2*3+0], p2y = pcb[i2*3+1], p2z = pcb[i2*3+2];
        float u1x = p2x - cx, u1y = p2y - cy, u1z = p2z - cz;
        float n1 = sqrtf(u1x*u1x + u1y*u1y + u1z*u1z) + 1e-8f;
        u1x /= n1; u1y /= n1; u1z /= n1;
        float vx = p0x - cx, vy = p0y - cy, vz = p0z - cz;
        float dot = vx*u1x + vy*u1y + vz*u1z;
        float u2x = vx - dot*u1x, u2y = vy - dot*u1y, u2z = vz - dot*u1z;
        float n2 = sqrtf(u2x*u2x + u2y*u2y + u2z*u2z) + 1e-8f;
        u2x /= n2; u2y /= n2; u2z /= n2;
        float u3x = u1y*u2z - u1z*u2y;
        float u3y = u1z*u2x - u1x*u2z;
        float u3z = u1x*u2y - u1y*u2x;
        Rs[tid][0]=u1x; Rs[tid][1]=u1y; Rs[tid][2]=u1z;
        Rs[tid][3]=u2x; Rs[tid][4]=u2y; Rs[tid][5]=u2z;
        Rs[tid][6]=u3x; Rs[tid][7]=u3y; Rs[tid][8]=u3z;
        cen[tid][0]=cx; cen[tid][1]=cy; cen[tid][2]=cz;
        const int ai = attr_idx[atom];
        float m = 0.f;
        #pragma unroll
        for (int a = 0; a < DA_; a++)
            if (attr_table[ai*DA_ + a] != 0.f) m = 1.f;
        const float mv = mask_atom[atom] * m;
        mvs[tid] = mv;
        mask_y[atom] = mv;
    }
    if (tid < 128) {
        const int t = tid >> 4, k = tid & 15;
        nbs[t][k] = nb_idx[(a0 + t) * K_ + k];
    }
    __syncthreads();

    if (tid < 128) {
        const int t = tid >> 4, k = tid & 15;
        const int j  = nbs[t][k];
        ais[t][k] = attr_idx[b * NA_ + j];
        const int fj = frame_idx[(b * NA_ + j) * 3 + 1];
        const float* pcb = pc + (size_t)b * NPC_ * 3;
        float dx = pcb[fj*3+0] - cen[t][0];
        float dy = pcb[fj*3+1] - cen[t][1];
        float dz = pcb[fj*3+2] - cen[t][2];
        rel[t][k][0] = Rs[t][0]*dx + Rs[t][1]*dy + Rs[t][2]*dz;
        rel[t][k][1] = Rs[t][3]*dx + Rs[t][4]*dy + Rs[t][5]*dz;
        rel[t][k][2] = Rs[t][6]*dx + Rs[t][7]*dy + Rs[t][8]*dz;
    }
    __syncthreads();

    for (int idx = tid; idx < 8 * K_ * DA_; idx += 256) {
        const int t = idx / (K_ * DA_);
        const int r = idx % (K_ * DA_);
        const int k = r / DA_, a = r % DA_;
        anb[t][k][a] = attr_table[ais[t][k] * DA_ + a];
    }
    __syncthreads();

    // per-thread: t = tid>>5 (atom), g = tid&31 (gaussian)
    {
        const int t = tid >> 5, g = tid & 31;
        const float gx = gauss[g*3+0], gy = gauss[g*3+1], gz = gauss[g*3+2];
        float acc[DA_];
        #pragma unroll
        for (int a = 0; a < DA_; a++) acc[a] = 0.f;
        #pragma unroll
        for (int k = 0; k < K_; k++) {
            const float dx = rel[t][k][0] - gx;
            const float dy = rel[t][k][1] - gy;
            const float dz = rel[t][k][2] - gz;
            const float gv = __expf(-0.5f * (dx*dx + dy*dy + dz*dz));
            #pragma unroll
            for (int a = 0; a < DA_; a++) acc[a] += gv * anb[t][k][a];
        }
        // write M[atom][g*12 .. g*12+12) as bf16 (6 packed u32)
        const int atom = a0 + t;
        unsigned int* dst = Mout + (size_t)atom * (384/2) + g * 6;
        #pragma unroll
        for (int i = 0; i < 6; i++) {
            const unsigned int lo = f2bf(acc[2*i]);
            const unsigned int hi = f2bf(acc[2*i+1]);
            dst[i] = lo | (hi << 16);
        }
    }
}

// ---------------------------------------------------------------------------
// k_g1: Y(32768x128,bf16) = M(32768x384,bf16) @ WnT^T, epilogue *(mask/16)
// block = 256 thr = 4 waves; block does 16 rows; wave does 2 n-tiles of 16.
// ---------------------------------------------------------------------------
__global__ __launch_bounds__(256) void k_g1(
    const unsigned short* __restrict__ M,
    const unsigned short* __restrict__ WnT,
    const float* __restrict__ masky,
    unsigned short* __restrict__ Y)
{
    const int mb   = blockIdx.x * 16;
    const int wave = threadIdx.x >> 6, lane = threadIdx.x & 63;
    const int l15  = lane & 15, quad = lane >> 4;
    const int n0   = wave * 32;

    const unsigned short* ap  = M   + (size_t)(mb + l15) * 384 + quad * 8;
    const unsigned short* bp0 = WnT + (size_t)(n0 + l15) * 384 + quad * 8;
    const unsigned short* bp1 = bp0 + (size_t)16 * 384;

    floatx4 acc0 = {0.f,0.f,0.f,0.f}, acc1 = {0.f,0.f,0.f,0.f};
    #pragma unroll
    for (int k0 = 0; k0 < 384; k0 += 32) {
        short8 a  = *reinterpret_cast<const short8*>(ap  + k0);
        short8 b0 = *reinterpret_cast<const short8*>(bp0 + k0);
        short8 b1 = *reinterpret_cast<const short8*>(bp1 + k0);
        acc0 = __builtin_amdgcn_mfma_f32_16x16x32_bf16(a, b0, acc0, 0, 0, 0);
        acc1 = __builtin_amdgcn_mfma_f32_16x16x32_bf16(a, b1, acc1, 0, 0, 0);
    }
    #pragma unroll
    for (int r = 0; r < 4; r++) {
        const int m = mb + quad * 4 + r;
        const float s = masky[m] * (1.f / 16.f);
        Y[(size_t)m * F_ + n0 + l15]      = f2bf(acc0[r] * s);
        Y[(size_t)m * F_ + n0 + 16 + l15] = f2bf(acc1[r] * s);
    }
}

// ---------------------------------------------------------------------------
// k_g2: AF(32768x256,bf16) = Y(32768x128,bf16) @ W2T^T, epilogue *mask
// block = 4 waves; 16 rows; wave does 4 n-tiles of 16 (64 cols).
// ---------------------------------------------------------------------------
__global__ __launch_bounds__(256) void k_g2(
    const unsigned short* __restrict__ Y,
    const unsigned short* __restrict__ W2T,
    const float* __restrict__ masky,
    unsigned short* __restrict__ AF)
{
    const int mb   = blockIdx.x * 16;
    const int wave = threadIdx.x >> 6, lane = threadIdx.x & 63;
    const int l15  = lane & 15, quad = lane >> 4;
    const int n0   = wave * 64;

    const unsigned short* ap = Y   + (size_t)(mb + l15) * F_ + quad * 8;
    const unsigned short* bp = W2T + (size_t)(n0 + l15) * F_ + quad * 8;

    floatx4 acc[4];
    #pragma unroll
    for (int t = 0; t < 4; t++) acc[t] = (floatx4){0.f,0.f,0.f,0.f};

    #pragma unroll
    for (int k0 = 0; k0 < 128; k0 += 32) {
        short8 a = *reinterpret_cast<const short8*>(ap + k0);
        #pragma unroll
        for (int t = 0; t < 4; t++) {
            short8 b = *reinterpret_cast<const short8*>(bp + (size_t)t * 16 * F_ + k0);
            acc[t] = __builtin_amdgcn_mfma_f32_16x16x32_bf16(a, b, acc[t], 0, 0, 0);
        }
    }
    #pragma unroll
    for (int r = 0; r < 4; r++) {
        const int m = mb + quad * 4 + r;
        const float s = masky[m];
        #pragma unroll
        for (int t = 0; t < 4; t++)
            AF[(size_t)m * 256 + n0 + t * 16 + l15] = f2bf(acc[t][r] * s);
    }
}

// ---------------------------------------------------------------------------
// k_pool: per-AA-row masked/gated softmax pooling (reads bf16 AF)
// ---------------------------------------------------------------------------
__global__ __launch_bounds__(128) void k_pool(
    const unsigned short* __restrict__ AF,
    const float* __restrict__ mask_y,
    const float* __restrict__ mask_aa,     // (B,NAA)
    const int* __restrict__ seq_idx_atom,  // (B,NA)
    const int* __restrict__ seq_idx_aa,    // (B,NAA)
    const int* __restrict__ aa_nb_idx,     // (B,NAA,14)
    float* __restrict__ pooled)
{
    const int row = blockIdx.x;       // b*NAA + i
    const int b   = row >> 10;        // NAA = 1024
    const int tid = threadIdx.x;

    __shared__ float gateS[KNC_], maskS[KNC_];
    __shared__ int   jS[KNC_];

    if (tid < KNC_) {
        const int j = aa_nb_idx[row * KNC_ + tid];
        jS[tid] = j;
        maskS[tid] = mask_y[b * NA_ + j];
        const int sa = seq_idx_aa[row];
        const int sn = seq_idx_atom[b * NA_ + j];
        gateS[tid] = (sn == sa) ? 1.f : 0.f;
    }
    __syncthreads();

    float av[KNC_], fv[KNC_];
    #pragma unroll
    for (int k = 0; k < KNC_; k++) {
        const size_t o = ((size_t)(b * NA_ + jS[k])) * 256 + tid;
        av[k] = bf2f(AF[o]);
        fv[k] = bf2f(AF[o + 128]);
    }
    float m = -1e30f;
    #pragma unroll
    for (int k = 0; k < KNC_; k++) {
        const float l = (maskS[k] > 0.f) ? av[k] : -1e9f;
        av[k] = l;
        m = fmaxf(m, l);
    }
    float s = 0.f;
    #pragma unroll
    for (int k = 0; k < KNC_; k++) { av[k] = __expf(av[k] - m); s += av[k]; }
    float tot = 0.f, p = 0.f;
    #pragma unroll
    for (int k = 0; k < KNC_; k++) {
        const float w = av[k] / s * gateS[k] * maskS[k];
        tot += w;
        p   += w * fv[k];
    }
    p = p / (tot + 1e-8f);
    p *= mask_aa[row];
    pooled[(size_t)row * F_ + tid] = p;
}

// ---------------------------------------------------------------------------
// k_stats
// ---------------------------------------------------------------------------
__global__ __launch_bounds__(128) void k_stats(
    const float* __restrict__ pooled,
    const float* __restrict__ mask_aa,
    float* __restrict__ stats)   // [0..127]=S1, [128..255]=S2, [256]=n
{
    const int tid = threadIdx.x;
    const int r0  = blockIdx.x * 128;
    float s1 = 0.f, s2 = 0.f;
    for (int r = 0; r < 128; r++) {
        const float v = pooled[(size_t)(r0 + r) * F_ + tid];
        s1 += v;
        s2 += v * v;
    }
    atomicAdd(&stats[tid], s1);
    atomicAdd(&stats[F_ + tid], s2);
    if (tid == 0) {
        float n = 0.f;
        for (int r = 0; r < 128; r++) n += mask_aa[r0 + r];
        atomicAdd(&stats[2 * F_], n);
    }
}

// ---------------------------------------------------------------------------
// k_final: batchnorm + relu + store; echo mask_aa as output 1
// ---------------------------------------------------------------------------
__global__ __launch_bounds__(256) void k_final(
    const float* __restrict__ pooled,
    const float* __restrict__ stats,
    const float* __restrict__ gamma,
    const float* __restrict__ beta,
    const float* __restrict__ mask_aa,
    float* __restrict__ out)
{
    const int idx = blockIdx.x * 256 + threadIdx.x;   // < B*NAA*D
    const int f   = idx & (D_ - 1);
    const int row = idx >> 7;
    const float n    = stats[2 * F_] + 1e-8f;
    const float mean = stats[f] / n;
    const float var  = stats[F_ + f] / n - mean * mean;
    const float ma   = mask_aa[row];
    float v = gamma[f] * (pooled[idx] - mean) * rsqrtf(var + 1e-5f) + beta[f];
    v = fmaxf(v * ma, 0.f);
    out[idx] = v;
    if (idx < B_ * NAA_) out[B_ * NAA_ * D_ + idx] = mask_aa[idx];
}

// ---------------------------------------------------------------------------
extern "C" void kernel_launch(void* const* d_in, const int* in_sizes, int n_in,
                              void* d_out, int out_size, void* d_ws, size_t ws_size,
                              hipStream_t stream) {
    const float* pc         = (const float*)d_in[0];
    const float* mask_atom  = (const float*)d_in[1];
    const float* mask_aa    = (const float*)d_in[2];
    const float* attr_table = (const float*)d_in[3];
    const float* gauss      = (const float*)d_in[4];
    const float* W_nem      = (const float*)d_in[5];
    const float* W_att      = (const float*)d_in[6];
    const float* W_feat     = (const float*)d_in[7];
    const float* gamma      = (const float*)d_in[8];
    const float* beta       = (const float*)d_in[9];
    const int* frame_idx    = (const int*)d_in[10];
    const int* attr_idx     = (const int*)d_in[11];
    const int* nb_idx       = (const int*)d_in[12];
    const int* seq_idx_atom = (const int*)d_in[13];
    const int* seq_idx_aa   = (const int*)d_in[14];
    const int* aa_nb_idx    = (const int*)d_in[15];

    // Workspace layout (bytes). M (25.2MB) and AF (16.8MB) alias: M is dead
    // after k_g1, AF is written by k_g2.
    char* base = (char*)d_ws;
    const size_t region0 = (size_t)32768 * 384 * 2;   // 25165824 (M; AF fits inside)
    unsigned short* M   = (unsigned short*)base;
    unsigned short* AF  = (unsigned short*)base;
    unsigned short* Y   = (unsigned short*)(base + region0);                 // 8.4 MB
    unsigned short* WnT = (unsigned short*)(base + region0 + 8388608);       // 96 KB
    unsigned short* W2T = (unsigned short*)(base + region0 + 8388608 + 98304); // 64 KB
    float* masky  = (float*)(base + region0 + 8388608 + 98304 + 65536);      // 128 KB
    float* pooled = (float*)(base + region0 + 8388608 + 98304 + 65536 + 131072); // 4.2 MB
    float* stats  = (float*)(base + region0 + 8388608 + 98304 + 65536 + 131072 + 4194304);

    hipMemsetAsync(stats, 0, 257 * sizeof(float), stream);

    k_prep<<<(128*384 + 256*128 + 255) / 256, 256, 0, stream>>>(
        W_nem, W_att, W_feat, WnT, W2T);
    k_geom<<<B_*NA_/8, 256, 0, stream>>>(pc, mask_atom, attr_table, gauss,
                                         frame_idx, attr_idx, nb_idx,
                                         (unsigned int*)M, masky);
    k_g1<<<B_*NA_/16, 256, 0, stream>>>(M, WnT, masky, Y);
    k_g2<<<B_*NA_/16, 256, 0, stream>>>(Y, W2T, masky, AF);
    k_pool<<<B_*NAA_, 128, 0, stream>>>(AF, masky, mask_aa,
                                        seq_idx_atom, seq_idx_aa, aa_nb_idx,
                                        pooled);
    k_stats<<<64, 128, 0, stream>>>(pooled, mask_aa, stats);
    k_final<<<(B_*NAA_*D_) / 256, 256, 0, stream>>>(pooled, stats, gamma, beta,
                                                    mask_aa, (float*)d_out);
}

// Round 4
// 171.724 us; speedup vs baseline: 2.1675x; 1.1382x over previous
//
#include <hip/hip_runtime.h>
#include <hip/hip_bf16.h>

// Problem constants
#define B_    8
#define NA_   4096
#define NAA_  1024
#define NPC_  4096
#define K_    16
#define KNC_  14
#define G_    32
#define DA_   12
#define F_    128
#define D_    128

typedef __attribute__((ext_vector_type(8))) short short8;
typedef __attribute__((ext_vector_type(4))) float floatx4;

__device__ __forceinline__ unsigned short f2bf(float x) {
    __hip_bfloat16 h = __float2bfloat16(x);
    return *reinterpret_cast<unsigned short*>(&h);
}
__device__ __forceinline__ float bf2f(unsigned short u) {
    __hip_bfloat16 h;
    *reinterpret_cast<unsigned short*>(&h) = u;
    return __bfloat162float(h);
}

// ---------------------------------------------------------------------------
// k_geom: frames + gaussian embedding + M (bf16) + mask_y.
// Blocks [0, 4096): geometry, 8 atoms/block, 256 threads.
// Blocks [4096, 4416): weight transpose prep (WnT, W2T) fused in.
// ---------------------------------------------------------------------------
__global__ __launch_bounds__(256) void k_geom(
    const float* __restrict__ pc,         // (B,NPC,3)
    const float* __restrict__ mask_atom,  // (B,NA)
    const float* __restrict__ attr_table, // (39,12)
    const float* __restrict__ gauss,      // (32,3)
    const int* __restrict__ frame_idx,    // (B,NA,3)
    const int* __restrict__ attr_idx,     // (B,NA)
    const int* __restrict__ nb_idx,       // (B,NA,16)
    const float* __restrict__ W_nem, const float* __restrict__ W_att,
    const float* __restrict__ W_feat,
    unsigned int* __restrict__ Mout,      // (32768, 384) bf16 as u32 pairs
    float* __restrict__ mask_y,
    unsigned short* __restrict__ WnT,     // (128, 384) bf16
    unsigned short* __restrict__ W2T)     // (256, 128) bf16
{
    const int tid = threadIdx.x;

    if (blockIdx.x >= 4096) {   // ---- prep branch ----
        const int idx = (blockIdx.x - 4096) * 256 + tid;   // < 81920
        if (idx < 128 * 384) {
            const int f = idx / 384, ga = idx % 384;
            WnT[idx] = f2bf(W_nem[(size_t)ga * F_ + f]);
        } else if (idx < 128 * 384 + 256 * 128) {
            const int j = idx - 128 * 384;
            const int n = j / 128, k = j % 128;
            const float v = (n < 128) ? W_att[(size_t)k * F_ + n]
                                      : W_feat[(size_t)k * F_ + (n - 128)];
            W2T[j] = f2bf(v);
        }
        return;
    }

    const int a0 = blockIdx.x * 8;
    const int b  = a0 >> 12;              // NA = 4096

    __shared__ float  Rs[8][9];
    __shared__ float  cen[8][3];
    __shared__ int    nbs[8][K_];
    __shared__ int    ais[8][K_];
    __shared__ __align__(16) float rel4[8][K_][4];
    __shared__ __align__(16) float anb4[8][K_][12];

    if (tid < 8) {
        const int atom = a0 + tid;
        const int fb = atom * 3;
        const int i0 = frame_idx[fb + 0];
        const int i1 = frame_idx[fb + 1];
        const int i2 = frame_idx[fb + 2];
        const float* pcb = pc + (size_t)b * NPC_ * 3;
        float p0x = pcb[i0*3+0], p0y = pcb[i0*3+1], p0z = pcb[i0*3+2];
        float cx  = pcb[i1*3+0], cy  = pcb[i1*3+1], cz  = pcb[i1*3+2];
        float p2x = pcb[i2*3+0], p2y = pcb[i2*3+1], p2z = pcb[i2*3+2];
        float u1x = p2x - cx, u1y = p2y - cy, u1z = p2z - cz;
        float n1 = sqrtf(u1x*u1x + u1y*u1y + u1z*u1z) + 1e-8f;
        u1x /= n1; u1y /= n1; u1z /= n1;
        float vx = p0x - cx, vy = p0y - cy, vz = p0z - cz;
        float dot = vx*u1x + vy*u1y + vz*u1z;
        float u2x = vx - dot*u1x, u2y = vy - dot*u1y, u2z = vz - dot*u1z;
        float n2 = sqrtf(u2x*u2x + u2y*u2y + u2z*u2z) + 1e-8f;
        u2x /= n2; u2y /= n2; u2z /= n2;
        float u3x = u1y*u2z - u1z*u2y;
        float u3y = u1z*u2x - u1x*u2z;
        float u3z = u1x*u2y - u1y*u2x;
        Rs[tid][0]=u1x; Rs[tid][1]=u1y; Rs[tid][2]=u1z;
        Rs[tid][3]=u2x; Rs[tid][4]=u2y; Rs[tid][5]=u2z;
        Rs[tid][6]=u3x; Rs[tid][7]=u3y; Rs[tid][8]=u3z;
        cen[tid][0]=cx; cen[tid][1]=cy; cen[tid][2]=cz;
        const int ai = attr_idx[atom];
        float m = 0.f;
        #pragma unroll
        for (int a = 0; a < DA_; a++)
            if (attr_table[ai*DA_ + a] != 0.f) m = 1.f;
        mask_y[atom] = mask_atom[atom] * m;
    }
    if (tid < 128) {
        const int t = tid >> 4, k = tid & 15;
        nbs[t][k] = nb_idx[(a0 + t) * K_ + k];
    }
    __syncthreads();

    if (tid < 128) {
        const int t = tid >> 4, k = tid & 15;
        const int j  = nbs[t][k];
        ais[t][k] = attr_idx[b * NA_ + j];
        const int fj = frame_idx[(b * NA_ + j) * 3 + 1];
        const float* pcb = pc + (size_t)b * NPC_ * 3;
        float dx = pcb[fj*3+0] - cen[t][0];
        float dy = pcb[fj*3+1] - cen[t][1];
        float dz = pcb[fj*3+2] - cen[t][2];
        rel4[t][k][0] = Rs[t][0]*dx + Rs[t][1]*dy + Rs[t][2]*dz;
        rel4[t][k][1] = Rs[t][3]*dx + Rs[t][4]*dy + Rs[t][5]*dz;
        rel4[t][k][2] = Rs[t][6]*dx + Rs[t][7]*dy + Rs[t][8]*dz;
        rel4[t][k][3] = 0.f;
    }
    __syncthreads();

    // anb4 fill: 8*16*3 = 384 float4 loads (attr rows are 48B = 16B-aligned)
    if (tid < 128) {
        const int t = tid >> 4, k = tid & 15;
        const float4* src = (const float4*)attr_table + (size_t)ais[t][k] * 3;
        float4* dst = (float4*)&anb4[t][k][0];
        dst[0] = src[0]; dst[1] = src[1]; dst[2] = src[2];
    }
    __syncthreads();

    // main contraction: thread = (atom t, gaussian g); LDS reads broadcast
    {
        const int t = tid >> 5, g = tid & 31;
        const float gx = gauss[g*3+0], gy = gauss[g*3+1], gz = gauss[g*3+2];
        float acc[DA_];
        #pragma unroll
        for (int a = 0; a < DA_; a++) acc[a] = 0.f;
        #pragma unroll
        for (int k = 0; k < K_; k++) {
            const float4 r  = *(const float4*)&rel4[t][k][0];
            const float dx = r.x - gx, dy = r.y - gy, dz = r.z - gz;
            const float gv = __expf(-0.5f * (dx*dx + dy*dy + dz*dz));
            const float4 a0 = *(const float4*)&anb4[t][k][0];
            const float4 a1 = *(const float4*)&anb4[t][k][4];
            const float4 a2 = *(const float4*)&anb4[t][k][8];
            acc[0] += gv*a0.x; acc[1] += gv*a0.y; acc[2] += gv*a0.z; acc[3] += gv*a0.w;
            acc[4] += gv*a1.x; acc[5] += gv*a1.y; acc[6] += gv*a1.z; acc[7] += gv*a1.w;
            acc[8] += gv*a2.x; acc[9] += gv*a2.y; acc[10]+= gv*a2.z; acc[11]+= gv*a2.w;
        }
        const int atom = a0 + t;
        unsigned int* dst = Mout + (size_t)atom * (384/2) + g * 6;
        #pragma unroll
        for (int i = 0; i < 6; i++) {
            const unsigned int lo = f2bf(acc[2*i]);
            const unsigned int hi = f2bf(acc[2*i+1]);
            dst[i] = lo | (hi << 16);
        }
    }
}

// ---------------------------------------------------------------------------
// k_gemm: fused  Y = (M @ WnT^T) * mask/16  (LDS)  then  AF = (Y @ W2T^T)*mask
// block = 256 thr = 4 waves, 32 rows/block.
// Stage 1: wave w -> cols [32w,32w+32), 2x2 MFMA tiles -> Ys in LDS.
// Stage 2: wave w -> cols [64w,64w+64), 2x4 MFMA tiles, A from LDS.
// ---------------------------------------------------------------------------
__global__ __launch_bounds__(256) void k_gemm(
    const unsigned short* __restrict__ M,     // (32768,384)
    const unsigned short* __restrict__ WnT,   // (128,384)
    const unsigned short* __restrict__ W2T,   // (256,128)
    const float* __restrict__ masky,
    unsigned short* __restrict__ AF)          // (32768,256)
{
    const int mb   = blockIdx.x * 32;
    const int wave = threadIdx.x >> 6, lane = threadIdx.x & 63;
    const int l15  = lane & 15, quad = lane >> 4;

    __shared__ __align__(16) unsigned short Ys[32][136];  // padded stride
    __shared__ float mk[32];

    if (threadIdx.x < 32) mk[threadIdx.x] = masky[mb + threadIdx.x];

    // ---- stage 1 ----
    const int n0 = wave * 32;
    const unsigned short* ap0 = M   + (size_t)(mb + l15) * 384 + quad * 8;
    const unsigned short* ap1 = ap0 + (size_t)16 * 384;
    const unsigned short* bp0 = WnT + (size_t)(n0 + l15) * 384 + quad * 8;
    const unsigned short* bp1 = bp0 + (size_t)16 * 384;

    floatx4 c00 = {0.f,0.f,0.f,0.f}, c01 = {0.f,0.f,0.f,0.f};
    floatx4 c10 = {0.f,0.f,0.f,0.f}, c11 = {0.f,0.f,0.f,0.f};
    #pragma unroll
    for (int k0 = 0; k0 < 384; k0 += 32) {
        short8 a0 = *reinterpret_cast<const short8*>(ap0 + k0);
        short8 a1 = *reinterpret_cast<const short8*>(ap1 + k0);
        short8 b0 = *reinterpret_cast<const short8*>(bp0 + k0);
        short8 b1 = *reinterpret_cast<const short8*>(bp1 + k0);
        c00 = __builtin_amdgcn_mfma_f32_16x16x32_bf16(a0, b0, c00, 0, 0, 0);
        c01 = __builtin_amdgcn_mfma_f32_16x16x32_bf16(a0, b1, c01, 0, 0, 0);
        c10 = __builtin_amdgcn_mfma_f32_16x16x32_bf16(a1, b0, c10, 0, 0, 0);
        c11 = __builtin_amdgcn_mfma_f32_16x16x32_bf16(a1, b1, c11, 0, 0, 0);
    }
    __syncthreads();   // mk visible
    #pragma unroll
    for (int r = 0; r < 4; r++) {
        const int r0 = quad * 4 + r;
        const float s0 = mk[r0]      * (1.f / 16.f);
        const float s1 = mk[16 + r0] * (1.f / 16.f);
        Ys[r0][n0 + l15]           = f2bf(c00[r] * s0);
        Ys[r0][n0 + 16 + l15]      = f2bf(c01[r] * s0);
        Ys[16 + r0][n0 + l15]      = f2bf(c10[r] * s1);
        Ys[16 + r0][n0 + 16 + l15] = f2bf(c11[r] * s1);
    }
    __syncthreads();

    // ---- stage 2 ----
    const int c0 = wave * 64;
    const unsigned short* bq = W2T + (size_t)(c0 + l15) * F_ + quad * 8;

    floatx4 f0[4], f1[4];
    #pragma unroll
    for (int t = 0; t < 4; t++) {
        f0[t] = (floatx4){0.f,0.f,0.f,0.f};
        f1[t] = (floatx4){0.f,0.f,0.f,0.f};
    }
    #pragma unroll
    for (int k0 = 0; k0 < 128; k0 += 32) {
        short8 a0 = *reinterpret_cast<const short8*>(&Ys[l15][k0 + quad * 8]);
        short8 a1 = *reinterpret_cast<const short8*>(&Ys[16 + l15][k0 + quad * 8]);
        #pragma unroll
        for (int t = 0; t < 4; t++) {
            short8 b = *reinterpret_cast<const short8*>(bq + (size_t)t * 16 * F_ + k0);
            f0[t] = __builtin_amdgcn_mfma_f32_16x16x32_bf16(a0, b, f0[t], 0, 0, 0);
            f1[t] = __builtin_amdgcn_mfma_f32_16x16x32_bf16(a1, b, f1[t], 0, 0, 0);
        }
    }
    #pragma unroll
    for (int r = 0; r < 4; r++) {
        const int r0 = quad * 4 + r;
        const float s0 = mk[r0], s1 = mk[16 + r0];
        unsigned short* o0 = AF + (size_t)(mb + r0) * 256 + c0 + l15;
        unsigned short* o1 = AF + (size_t)(mb + 16 + r0) * 256 + c0 + l15;
        #pragma unroll
        for (int t = 0; t < 4; t++) {
            o0[t * 16] = f2bf(f0[t][r] * s0);
            o1[t * 16] = f2bf(f1[t][r] * s1);
        }
    }
}

// ---------------------------------------------------------------------------
// k_pool: per-AA-row masked/gated softmax pooling; 2 rows per block.
// ---------------------------------------------------------------------------
__global__ __launch_bounds__(256) void k_pool(
    const unsigned short* __restrict__ AF,
    const float* __restrict__ mask_y,
    const float* __restrict__ mask_aa,     // (B,NAA)
    const int* __restrict__ seq_idx_atom,  // (B,NA)
    const int* __restrict__ seq_idx_aa,    // (B,NAA)
    const int* __restrict__ aa_nb_idx,     // (B,NAA,14)
    float* __restrict__ pooled)
{
    const int tid = threadIdx.x;
    const int rl  = tid >> 7;              // 0..1
    const int f   = tid & 127;
    const int row = blockIdx.x * 2 + rl;   // b*NAA + i
    const int b   = row >> 10;             // NAA = 1024

    __shared__ float gateS[2][KNC_], maskS[2][KNC_];
    __shared__ int   jS[2][KNC_];

    if (tid < 2 * KNC_) {
        const int r = tid / KNC_, k = tid % KNC_;
        const int rr = blockIdx.x * 2 + r;
        const int j = aa_nb_idx[rr * KNC_ + k];
        jS[r][k] = j;
        maskS[r][k] = mask_y[(rr >> 10) * NA_ + j];
        const int sa = seq_idx_aa[rr];
        const int sn = seq_idx_atom[(rr >> 10) * NA_ + j];
        gateS[r][k] = (sn == sa) ? 1.f : 0.f;
    }
    __syncthreads();

    float av[KNC_], fv[KNC_];
    #pragma unroll
    for (int k = 0; k < KNC_; k++) {
        const size_t o = ((size_t)(b * NA_ + jS[rl][k])) * 256 + f;
        av[k] = bf2f(AF[o]);
        fv[k] = bf2f(AF[o + 128]);
    }
    float m = -1e30f;
    #pragma unroll
    for (int k = 0; k < KNC_; k++) {
        const float l = (maskS[rl][k] > 0.f) ? av[k] : -1e9f;
        av[k] = l;
        m = fmaxf(m, l);
    }
    float s = 0.f;
    #pragma unroll
    for (int k = 0; k < KNC_; k++) { av[k] = __expf(av[k] - m); s += av[k]; }
    float tot = 0.f, p = 0.f;
    #pragma unroll
    for (int k = 0; k < KNC_; k++) {
        const float w = av[k] / s * gateS[rl][k] * maskS[rl][k];
        tot += w;
        p   += w * fv[k];
    }
    p = p / (tot + 1e-8f);
    p *= mask_aa[row];
    pooled[(size_t)row * F_ + f] = p;
}

// ---------------------------------------------------------------------------
// k_stats
// ---------------------------------------------------------------------------
__global__ __launch_bounds__(128) void k_stats(
    const float* __restrict__ pooled,
    const float* __restrict__ mask_aa,
    float* __restrict__ stats)   // [0..127]=S1, [128..255]=S2, [256]=n
{
    const int tid = threadIdx.x;
    const int r0  = blockIdx.x * 128;
    float s1 = 0.f, s2 = 0.f;
    for (int r = 0; r < 128; r++) {
        const float v = pooled[(size_t)(r0 + r) * F_ + tid];
        s1 += v;
        s2 += v * v;
    }
    atomicAdd(&stats[tid], s1);
    atomicAdd(&stats[F_ + tid], s2);
    if (tid == 0) {
        float n = 0.f;
        for (int r = 0; r < 128; r++) n += mask_aa[r0 + r];
        atomicAdd(&stats[2 * F_], n);
    }
}

// ---------------------------------------------------------------------------
// k_final: batchnorm + relu + store; echo mask_aa as output 1
// ---------------------------------------------------------------------------
__global__ __launch_bounds__(256) void k_final(
    const float* __restrict__ pooled,
    const float* __restrict__ stats,
    const float* __restrict__ gamma,
    const float* __restrict__ beta,
    const float* __restrict__ mask_aa,
    float* __restrict__ out)
{
    const int idx = blockIdx.x * 256 + threadIdx.x;   // < B*NAA*D
    const int f   = idx & (D_ - 1);
    const int row = idx >> 7;
    const float n    = stats[2 * F_] + 1e-8f;
    const float mean = stats[f] / n;
    const float var  = stats[F_ + f] / n - mean * mean;
    const float ma   = mask_aa[row];
    float v = gamma[f] * (pooled[idx] - mean) * rsqrtf(var + 1e-5f) + beta[f];
    v = fmaxf(v * ma, 0.f);
    out[idx] = v;
    if (idx < B_ * NAA_) out[B_ * NAA_ * D_ + idx] = mask_aa[idx];
}

// ---------------------------------------------------------------------------
extern "C" void kernel_launch(void* const* d_in, const int* in_sizes, int n_in,
                              void* d_out, int out_size, void* d_ws, size_t ws_size,
                              hipStream_t stream) {
    const float* pc         = (const float*)d_in[0];
    const float* mask_atom  = (const float*)d_in[1];
    const float* mask_aa    = (const float*)d_in[2];
    const float* attr_table = (const float*)d_in[3];
    const float* gauss      = (const float*)d_in[4];
    const float* W_nem      = (const float*)d_in[5];
    const float* W_att      = (const float*)d_in[6];
    const float* W_feat     = (const float*)d_in[7];
    const float* gamma      = (const float*)d_in[8];
    const float* beta       = (const float*)d_in[9];
    const int* frame_idx    = (const int*)d_in[10];
    const int* attr_idx     = (const int*)d_in[11];
    const int* nb_idx       = (const int*)d_in[12];
    const int* seq_idx_atom = (const int*)d_in[13];
    const int* seq_idx_aa   = (const int*)d_in[14];
    const int* aa_nb_idx    = (const int*)d_in[15];

    // Workspace layout. M (25.2MB) and AF (16.8MB) alias: M dead after stage1
    // of k_gemm consumes it... NOT aliased here: k_gemm reads M while writing
    // AF. Keep disjoint (total ~47MB << 268MB ws).
    char* base = (char*)d_ws;
    unsigned short* M   = (unsigned short*)base;                              // 25165824
    unsigned short* AF  = (unsigned short*)(base + 25165824);                 // 16777216
    unsigned short* WnT = (unsigned short*)(base + 25165824 + 16777216);      // 98304
    unsigned short* W2T = (unsigned short*)(base + 25165824 + 16777216 + 98304); // 65536
    float* masky  = (float*)(base + 25165824 + 16777216 + 98304 + 65536);     // 131072
    float* pooled = (float*)(base + 25165824 + 16777216 + 98304 + 65536 + 131072); // 4194304
    float* stats  = (float*)(base + 25165824 + 16777216 + 98304 + 65536 + 131072 + 4194304);

    hipMemsetAsync(stats, 0, 257 * sizeof(float), stream);

    k_geom<<<4096 + 320, 256, 0, stream>>>(pc, mask_atom, attr_table, gauss,
                                           frame_idx, attr_idx, nb_idx,
                                           W_nem, W_att, W_feat,
                                           (unsigned int*)M, masky, WnT, W2T);
    k_gemm<<<B_*NA_/32, 256, 0, stream>>>(M, WnT, W2T, masky, AF);
    k_pool<<<B_*NAA_/2, 256, 0, stream>>>(AF, masky, mask_aa,
                                          seq_idx_atom, seq_idx_aa, aa_nb_idx,
                                          pooled);
    k_stats<<<64, 128, 0, stream>>>(pooled, mask_aa, stats);
    k_final<<<(B_*NAA_*D_) / 256, 256, 0, stream>>>(pooled, stats, gamma, beta,
                                                    mask_aa, (float*)d_out);
}

// Round 5
// 166.389 us; speedup vs baseline: 2.2370x; 1.0321x over previous
//
#include <hip/hip_runtime.h>
#include <hip/hip_bf16.h>

// Problem constants
#define B_    8
#define NA_   4096
#define NAA_  1024
#define NPC_  4096
#define K_    16
#define KNC_  14
#define G_    32
#define DA_   12
#define F_    128
#define D_    128

typedef __attribute__((ext_vector_type(8))) short short8;
typedef __attribute__((ext_vector_type(4))) float floatx4;

__device__ __forceinline__ unsigned short f2bf(float x) {
    __hip_bfloat16 h = __float2bfloat16(x);
    return *reinterpret_cast<unsigned short*>(&h);
}
__device__ __forceinline__ float bf2f(unsigned short u) {
    __hip_bfloat16 h;
    *reinterpret_cast<unsigned short*>(&h) = u;
    return __bfloat162float(h);
}
__device__ __forceinline__ float bflo(unsigned int u) {   // low bf16 of pair
    return __uint_as_float(u << 16);
}
__device__ __forceinline__ float bfhi(unsigned int u) {   // high bf16 of pair
    return __uint_as_float(u & 0xffff0000u);
}

// ---------------------------------------------------------------------------
// k_prep: transpose weights to bf16.
//   WnT[f][ga] = W_nem[ga][f]          (128 x 384)
//   W2T[n][k]  = n<128 ? W_att[k][n] : W_feat[k][n-128]   (256 x 128)
// ---------------------------------------------------------------------------
__global__ __launch_bounds__(256) void k_prep(
    const float* __restrict__ W_nem, const float* __restrict__ W_att,
    const float* __restrict__ W_feat,
    unsigned short* __restrict__ WnT, unsigned short* __restrict__ W2T)
{
    const int idx = blockIdx.x * 256 + threadIdx.x;   // < 81920
    if (idx < 128 * 384) {
        const int f = idx / 384, ga = idx % 384;
        WnT[idx] = f2bf(W_nem[(size_t)ga * F_ + f]);
    } else if (idx < 128 * 384 + 256 * 128) {
        const int j = idx - 128 * 384;
        const int n = j / 128, k = j % 128;
        const float v = (n < 128) ? W_att[(size_t)k * F_ + n]
                                  : W_feat[(size_t)k * F_ + (n - 128)];
        W2T[j] = f2bf(v);
    }
}

// ---------------------------------------------------------------------------
// k_fused: geometry -> M (LDS) -> Y (LDS) -> AF (global), 32 atoms/block.
// 256 threads = 4 waves.
//   geometry: frames, gaussian embedding, M[32][384] bf16 in LDS
//   stage1:   Y = (M @ WnT^T) * mask/16     (wave w: cols [32w,32w+32))
//   stage2:   AF = (Y @ W2T^T) * mask       (wave w: cols [64w,64w+64))
// ---------------------------------------------------------------------------
__global__ __launch_bounds__(256, 3) void k_fused(
    const float* __restrict__ pc,         // (B,NPC,3)
    const float* __restrict__ mask_atom,  // (B,NA)
    const float* __restrict__ attr_table, // (39,12)
    const float* __restrict__ gauss,      // (32,3)
    const int* __restrict__ frame_idx,    // (B,NA,3)
    const int* __restrict__ attr_idx,     // (B,NA)
    const int* __restrict__ nb_idx,       // (B,NA,16)
    const unsigned short* __restrict__ WnT,   // (128,384)
    const unsigned short* __restrict__ W2T,   // (256,128)
    float* __restrict__ mask_y,
    unsigned short* __restrict__ AF)          // (32768,256)
{
    const int a0  = blockIdx.x * 32;      // first atom
    const int b   = a0 >> 12;             // NA = 4096
    const int tid = threadIdx.x;
    const int wave = tid >> 6, lane = tid & 63;
    const int l15 = lane & 15, quad = lane >> 4;

    __shared__ unsigned short Ms[32][392];          // 25088 B (pad: stride 392)
    __shared__ __align__(16) char geo_union[20480]; // rel4+anbP | Ys
    __shared__ float Rs[32][9];
    __shared__ float cen[32][3];
    __shared__ float mk[32];

    float4        (*rel4)[K_]    = (float4(*)[K_])geo_union;            // 8192 B
    unsigned int  (*anbP)[K_][6] = (unsigned int(*)[K_][6])(geo_union + 8192); // 12288 B
    unsigned short(*Ys)[136]     = (unsigned short(*)[136])geo_union;   // 8704 B

    // ---- phase A: frames + masks (threads 0..31) ----
    if (tid < 32) {
        const int atom = a0 + tid;
        const int fb = atom * 3;
        const int i0 = frame_idx[fb + 0];
        const int i1 = frame_idx[fb + 1];
        const int i2 = frame_idx[fb + 2];
        const float* pcb = pc + (size_t)b * NPC_ * 3;
        float p0x = pcb[i0*3+0], p0y = pcb[i0*3+1], p0z = pcb[i0*3+2];
        float cx  = pcb[i1*3+0], cy  = pcb[i1*3+1], cz  = pcb[i1*3+2];
        float p2x = pcb[i2*3+0], p2y = pcb[i2*3+1], p2z = pcb[i2*3+2];
        float u1x = p2x - cx, u1y = p2y - cy, u1z = p2z - cz;
        float n1 = sqrtf(u1x*u1x + u1y*u1y + u1z*u1z) + 1e-8f;
        u1x /= n1; u1y /= n1; u1z /= n1;
        float vx = p0x - cx, vy = p0y - cy, vz = p0z - cz;
        float dot = vx*u1x + vy*u1y + vz*u1z;
        float u2x = vx - dot*u1x, u2y = vy - dot*u1y, u2z = vz - dot*u1z;
        float n2 = sqrtf(u2x*u2x + u2y*u2y + u2z*u2z) + 1e-8f;
        u2x /= n2; u2y /= n2; u2z /= n2;
        float u3x = u1y*u2z - u1z*u2y;
        float u3y = u1z*u2x - u1x*u2z;
        float u3z = u1x*u2y - u1y*u2x;
        Rs[tid][0]=u1x; Rs[tid][1]=u1y; Rs[tid][2]=u1z;
        Rs[tid][3]=u2x; Rs[tid][4]=u2y; Rs[tid][5]=u2z;
        Rs[tid][6]=u3x; Rs[tid][7]=u3y; Rs[tid][8]=u3z;
        cen[tid][0]=cx; cen[tid][1]=cy; cen[tid][2]=cz;
        const int ai = attr_idx[atom];
        float m = 0.f;
        #pragma unroll
        for (int a = 0; a < DA_; a++)
            if (attr_table[ai*DA_ + a] != 0.f) m = 1.f;
        const float mv = mask_atom[atom] * m;
        mk[tid] = mv;
        mask_y[atom] = mv;
    }
    __syncthreads();

    // ---- phase B: rel coords + packed neighbor attrs (512 tasks, 2 iters) --
    #pragma unroll
    for (int it = 0; it < 2; it++) {
        const int idx = tid + it * 256;          // < 512
        const int t = idx >> 4, k = idx & 15;
        const int j  = nb_idx[(a0 + t) * K_ + k];
        const int ai = attr_idx[b * NA_ + j];
        const int fj = frame_idx[(b * NA_ + j) * 3 + 1];
        const float* pcb = pc + (size_t)b * NPC_ * 3;
        float dx = pcb[fj*3+0] - cen[t][0];
        float dy = pcb[fj*3+1] - cen[t][1];
        float dz = pcb[fj*3+2] - cen[t][2];
        float4 r;
        r.x = Rs[t][0]*dx + Rs[t][1]*dy + Rs[t][2]*dz;
        r.y = Rs[t][3]*dx + Rs[t][4]*dy + Rs[t][5]*dz;
        r.z = Rs[t][6]*dx + Rs[t][7]*dy + Rs[t][8]*dz;
        r.w = 0.f;
        rel4[t][k] = r;
        const float4* src = (const float4*)attr_table + (size_t)ai * 3;
        #pragma unroll
        for (int q = 0; q < 3; q++) {
            const float4 v = src[q];
            anbP[t][k][q*2]   = (unsigned int)f2bf(v.x) | ((unsigned int)f2bf(v.y) << 16);
            anbP[t][k][q*2+1] = (unsigned int)f2bf(v.z) | ((unsigned int)f2bf(v.w) << 16);
        }
    }
    __syncthreads();

    // ---- phase C: contraction -> Ms (1024 tasks, 4 iters) ----
    #pragma unroll
    for (int it = 0; it < 4; it++) {
        const int idx = tid + it * 256;          // < 1024
        const int t = idx >> 5, g = idx & 31;
        const float gx = gauss[g*3+0], gy = gauss[g*3+1], gz = gauss[g*3+2];
        float acc[DA_];
        #pragma unroll
        for (int a = 0; a < DA_; a++) acc[a] = 0.f;
        #pragma unroll
        for (int k = 0; k < K_; k++) {
            const float4 r = rel4[t][k];
            const float dx = r.x - gx, dy = r.y - gy, dz = r.z - gz;
            const float gv = __expf(-0.5f * (dx*dx + dy*dy + dz*dz));
            #pragma unroll
            for (int q = 0; q < 6; q++) {
                const unsigned int u = anbP[t][k][q];
                acc[2*q]   += gv * bflo(u);
                acc[2*q+1] += gv * bfhi(u);
            }
        }
        unsigned int* dst = (unsigned int*)&Ms[t][g * 12];
        #pragma unroll
        for (int i = 0; i < 6; i++) {
            const unsigned int lo = f2bf(acc[2*i]);
            const unsigned int hi = f2bf(acc[2*i+1]);
            dst[i] = lo | (hi << 16);
        }
    }
    __syncthreads();

    // ---- stage 1: Y = (M @ WnT^T) * mask/16, into Ys (aliases geo) ----
    const int n0 = wave * 32;
    const unsigned short* bp0 = WnT + (size_t)(n0 + l15) * 384 + quad * 8;
    const unsigned short* bp1 = bp0 + (size_t)16 * 384;

    floatx4 c00 = {0.f,0.f,0.f,0.f}, c01 = {0.f,0.f,0.f,0.f};
    floatx4 c10 = {0.f,0.f,0.f,0.f}, c11 = {0.f,0.f,0.f,0.f};
    #pragma unroll
    for (int k0 = 0; k0 < 384; k0 += 32) {
        short8 a0v = *reinterpret_cast<const short8*>(&Ms[l15][quad * 8 + k0]);
        short8 a1v = *reinterpret_cast<const short8*>(&Ms[16 + l15][quad * 8 + k0]);
        short8 b0 = *reinterpret_cast<const short8*>(bp0 + k0);
        short8 b1 = *reinterpret_cast<const short8*>(bp1 + k0);
        c00 = __builtin_amdgcn_mfma_f32_16x16x32_bf16(a0v, b0, c00, 0, 0, 0);
        c01 = __builtin_amdgcn_mfma_f32_16x16x32_bf16(a0v, b1, c01, 0, 0, 0);
        c10 = __builtin_amdgcn_mfma_f32_16x16x32_bf16(a1v, b0, c10, 0, 0, 0);
        c11 = __builtin_amdgcn_mfma_f32_16x16x32_bf16(a1v, b1, c11, 0, 0, 0);
    }
    __syncthreads();   // all geo reads done; safe to overwrite with Ys
    #pragma unroll
    for (int r = 0; r < 4; r++) {
        const int r0 = quad * 4 + r;
        const float s0 = mk[r0]      * (1.f / 16.f);
        const float s1 = mk[16 + r0] * (1.f / 16.f);
        Ys[r0][n0 + l15]           = f2bf(c00[r] * s0);
        Ys[r0][n0 + 16 + l15]      = f2bf(c01[r] * s0);
        Ys[16 + r0][n0 + l15]      = f2bf(c10[r] * s1);
        Ys[16 + r0][n0 + 16 + l15] = f2bf(c11[r] * s1);
    }
    __syncthreads();

    // ---- stage 2: AF = (Y @ W2T^T) * mask ----
    const int c0 = wave * 64;
    const unsigned short* bq = W2T + (size_t)(c0 + l15) * F_ + quad * 8;

    floatx4 f0[4], f1[4];
    #pragma unroll
    for (int t = 0; t < 4; t++) {
        f0[t] = (floatx4){0.f,0.f,0.f,0.f};
        f1[t] = (floatx4){0.f,0.f,0.f,0.f};
    }
    #pragma unroll
    for (int k0 = 0; k0 < 128; k0 += 32) {
        short8 a0v = *reinterpret_cast<const short8*>(&Ys[l15][k0 + quad * 8]);
        short8 a1v = *reinterpret_cast<const short8*>(&Ys[16 + l15][k0 + quad * 8]);
        #pragma unroll
        for (int t = 0; t < 4; t++) {
            short8 bv = *reinterpret_cast<const short8*>(bq + (size_t)t * 16 * F_ + k0);
            f0[t] = __builtin_amdgcn_mfma_f32_16x16x32_bf16(a0v, bv, f0[t], 0, 0, 0);
            f1[t] = __builtin_amdgcn_mfma_f32_16x16x32_bf16(a1v, bv, f1[t], 0, 0, 0);
        }
    }
    #pragma unroll
    for (int r = 0; r < 4; r++) {
        const int r0 = quad * 4 + r;
        const float s0 = mk[r0], s1 = mk[16 + r0];
        unsigned short* o0 = AF + (size_t)(a0 + r0) * 256 + c0 + l15;
        unsigned short* o1 = AF + (size_t)(a0 + 16 + r0) * 256 + c0 + l15;
        #pragma unroll
        for (int t = 0; t < 4; t++) {
            o0[t * 16] = f2bf(f0[t][r] * s0);
            o1[t * 16] = f2bf(f1[t][r] * s1);
        }
    }
}

// ---------------------------------------------------------------------------
// k_pool_stats: masked/gated softmax pooling (8 rows/block) + fused stats.
// 256 threads: rl = tid>>7 handles rows {rl, rl+2, rl+4, rl+6}.
// ---------------------------------------------------------------------------
__global__ __launch_bounds__(256) void k_pool_stats(
    const unsigned short* __restrict__ AF,
    const float* __restrict__ mask_y,
    const float* __restrict__ mask_aa,     // (B,NAA)
    const int* __restrict__ seq_idx_atom,  // (B,NA)
    const int* __restrict__ seq_idx_aa,    // (B,NAA)
    const int* __restrict__ aa_nb_idx,     // (B,NAA,14)
    float* __restrict__ pooled,
    float* __restrict__ stats)             // [0..127]=S1,[128..255]=S2,[256]=n
{
    const int tid  = threadIdx.x;
    const int rl   = tid >> 7;             // 0..1
    const int f    = tid & 127;
    const int row0 = blockIdx.x * 8;

    __shared__ float gateS[8][KNC_], maskS[8][KNC_];
    __shared__ int   jS[8][KNC_];
    __shared__ float red[128];

    if (tid < 8 * KNC_) {
        const int r = tid / KNC_, k = tid % KNC_;
        const int rr = row0 + r;
        const int bb = rr >> 10;
        const int j = aa_nb_idx[rr * KNC_ + k];
        jS[r][k] = j;
        maskS[r][k] = mask_y[bb * NA_ + j];
        const int sa = seq_idx_aa[rr];
        const int sn = seq_idx_atom[bb * NA_ + j];
        gateS[r][k] = (sn == sa) ? 1.f : 0.f;
    }
    __syncthreads();

    float s1 = 0.f, s2 = 0.f;
    #pragma unroll
    for (int it = 0; it < 4; it++) {
        const int r   = it * 2 + rl;
        const int row = row0 + r;
        const int bb  = row >> 10;

        float av[KNC_], fv[KNC_];
        #pragma unroll
        for (int k = 0; k < KNC_; k++) {
            const size_t o = ((size_t)(bb * NA_ + jS[r][k])) * 256 + f;
            av[k] = bf2f(AF[o]);
            fv[k] = bf2f(AF[o + 128]);
        }
        float m = -1e30f;
        #pragma unroll
        for (int k = 0; k < KNC_; k++) {
            const float l = (maskS[r][k] > 0.f) ? av[k] : -1e9f;
            av[k] = l;
            m = fmaxf(m, l);
        }
        float s = 0.f;
        #pragma unroll
        for (int k = 0; k < KNC_; k++) { av[k] = __expf(av[k] - m); s += av[k]; }
        float tot = 0.f, p = 0.f;
        #pragma unroll
        for (int k = 0; k < KNC_; k++) {
            const float w = av[k] / s * gateS[r][k] * maskS[r][k];
            tot += w;
            p   += w * fv[k];
        }
        p = p / (tot + 1e-8f);
        p *= mask_aa[row];
        pooled[(size_t)row * F_ + f] = p;
        s1 += p;
        s2 += p * p;
    }

    // reduce rl=1 into rl=0, one atomic per feature per block
    if (rl == 1) red[f] = s1;
    __syncthreads();
    if (rl == 0) atomicAdd(&stats[f], s1 + red[f]);
    __syncthreads();
    if (rl == 1) red[f] = s2;
    __syncthreads();
    if (rl == 0) atomicAdd(&stats[F_ + f], s2 + red[f]);
    if (tid == 0) {
        float n = 0.f;
        #pragma unroll
        for (int r = 0; r < 8; r++) n += mask_aa[row0 + r];
        atomicAdd(&stats[2 * F_], n);
    }
}

// ---------------------------------------------------------------------------
// k_final: batchnorm + relu + store; echo mask_aa as output 1
// ---------------------------------------------------------------------------
__global__ __launch_bounds__(256) void k_final(
    const float* __restrict__ pooled,
    const float* __restrict__ stats,
    const float* __restrict__ gamma,
    const float* __restrict__ beta,
    const float* __restrict__ mask_aa,
    float* __restrict__ out)
{
    const int idx = blockIdx.x * 256 + threadIdx.x;   // < B*NAA*D
    const int f   = idx & (D_ - 1);
    const int row = idx >> 7;
    const float n    = stats[2 * F_] + 1e-8f;
    const float mean = stats[f] / n;
    const float var  = stats[F_ + f] / n - mean * mean;
    const float ma   = mask_aa[row];
    float v = gamma[f] * (pooled[idx] - mean) * rsqrtf(var + 1e-5f) + beta[f];
    v = fmaxf(v * ma, 0.f);
    out[idx] = v;
    if (idx < B_ * NAA_) out[B_ * NAA_ * D_ + idx] = mask_aa[idx];
}

// ---------------------------------------------------------------------------
extern "C" void kernel_launch(void* const* d_in, const int* in_sizes, int n_in,
                              void* d_out, int out_size, void* d_ws, size_t ws_size,
                              hipStream_t stream) {
    const float* pc         = (const float*)d_in[0];
    const float* mask_atom  = (const float*)d_in[1];
    const float* mask_aa    = (const float*)d_in[2];
    const float* attr_table = (const float*)d_in[3];
    const float* gauss      = (const float*)d_in[4];
    const float* W_nem      = (const float*)d_in[5];
    const float* W_att      = (const float*)d_in[6];
    const float* W_feat     = (const float*)d_in[7];
    const float* gamma      = (const float*)d_in[8];
    const float* beta       = (const float*)d_in[9];
    const int* frame_idx    = (const int*)d_in[10];
    const int* attr_idx     = (const int*)d_in[11];
    const int* nb_idx       = (const int*)d_in[12];
    const int* seq_idx_atom = (const int*)d_in[13];
    const int* seq_idx_aa   = (const int*)d_in[14];
    const int* aa_nb_idx    = (const int*)d_in[15];

    // Workspace layout (~21.3 MB of the provided ws)
    char* base = (char*)d_ws;
    unsigned short* AF  = (unsigned short*)base;                         // 16777216
    unsigned short* WnT = (unsigned short*)(base + 16777216);            // 98304
    unsigned short* W2T = (unsigned short*)(base + 16777216 + 98304);    // 65536
    float* masky  = (float*)(base + 16777216 + 98304 + 65536);           // 131072
    float* pooled = (float*)(base + 16777216 + 98304 + 65536 + 131072);  // 4194304
    float* stats  = (float*)(base + 16777216 + 98304 + 65536 + 131072 + 4194304);

    hipMemsetAsync(stats, 0, 257 * sizeof(float), stream);

    k_prep<<<320, 256, 0, stream>>>(W_nem, W_att, W_feat, WnT, W2T);
    k_fused<<<B_*NA_/32, 256, 0, stream>>>(pc, mask_atom, attr_table, gauss,
                                           frame_idx, attr_idx, nb_idx,
                                           WnT, W2T, masky, AF);
    k_pool_stats<<<B_*NAA_/8, 256, 0, stream>>>(AF, masky, mask_aa,
                                                seq_idx_atom, seq_idx_aa,
                                                aa_nb_idx, pooled, stats);
    k_final<<<(B_*NAA_*D_) / 256, 256, 0, stream>>>(pooled, stats, gamma, beta,
                                                    mask_aa, (float*)d_out);
}

// Round 7
// 151.210 us; speedup vs baseline: 2.4616x; 1.1004x over previous
//
#include <hip/hip_runtime.h>
#include <hip/hip_bf16.h>

// Problem constants
#define B_    8
#define NA_   4096
#define NAA_  1024
#define NPC_  4096
#define K_    16
#define KNC_  14
#define G_    32
#define DA_   12
#define F_    128
#define D_    128

typedef __attribute__((ext_vector_type(8))) short short8;
typedef __attribute__((ext_vector_type(4))) float floatx4;

__device__ __forceinline__ unsigned short f2bf(float x) {
    __hip_bfloat16 h = __float2bfloat16(x);
    return *reinterpret_cast<unsigned short*>(&h);
}
__device__ __forceinline__ float bf2f(unsigned short u) {
    __hip_bfloat16 h;
    *reinterpret_cast<unsigned short*>(&h) = u;
    return __bfloat162float(h);
}
__device__ __forceinline__ float bflo(unsigned int u) {   // low bf16 of pair
    return __uint_as_float(u << 16);
}
__device__ __forceinline__ float bfhi(unsigned int u) {   // high bf16 of pair
    return __uint_as_float(u & 0xffff0000u);
}

// ---------------------------------------------------------------------------
// k_prep: transpose weights to bf16 + zero stats (block 320).
//   WnT[f][ga] = W_nem[ga][f]          (128 x 384)
//   W2T[n][k]  = n<128 ? W_att[k][n] : W_feat[k][n-128]   (256 x 128)
// ---------------------------------------------------------------------------
__global__ __launch_bounds__(256) void k_prep(
    const float* __restrict__ W_nem, const float* __restrict__ W_att,
    const float* __restrict__ W_feat,
    unsigned short* __restrict__ WnT, unsigned short* __restrict__ W2T,
    float* __restrict__ stats)   // 257 floats: S1[128],S2[128],n
{
    if (blockIdx.x == 320) {
        if (threadIdx.x < 257) stats[threadIdx.x] = 0.f;
        return;
    }
    const int idx = blockIdx.x * 256 + threadIdx.x;   // < 81920
    if (idx < 128 * 384) {
        const int f = idx / 384, ga = idx % 384;
        WnT[idx] = f2bf(W_nem[(size_t)ga * F_ + f]);
    } else if (idx < 128 * 384 + 256 * 128) {
        const int j = idx - 128 * 384;
        const int n = j / 128, k = j % 128;
        const float v = (n < 128) ? W_att[(size_t)k * F_ + n]
                                  : W_feat[(size_t)k * F_ + (n - 128)];
        W2T[j] = f2bf(v);
    }
}

// ---------------------------------------------------------------------------
// k_fused: geometry -> M (LDS) -> Y (LDS) -> AF (global), 32 atoms/block.
// LDS: Ms region (25088B) aliased by geometry buffers (20480B); Ys separate.
// Total ~35.5 KB -> 4 blocks/CU with __launch_bounds__(256,4).
// ---------------------------------------------------------------------------
__global__ __launch_bounds__(256, 4) void k_fused(
    const float* __restrict__ pc,         // (B,NPC,3)
    const float* __restrict__ mask_atom,  // (B,NA)
    const float* __restrict__ attr_table, // (39,12)
    const float* __restrict__ gauss,      // (32,3)
    const int* __restrict__ frame_idx,    // (B,NA,3)
    const int* __restrict__ attr_idx,     // (B,NA)
    const int* __restrict__ nb_idx,       // (B,NA,16)
    const unsigned short* __restrict__ WnT,   // (128,384)
    const unsigned short* __restrict__ W2T,   // (256,128)
    float* __restrict__ mask_y,
    unsigned short* __restrict__ AF)          // (32768,256)
{
    const int a0  = blockIdx.x * 32;      // first atom
    const int b   = a0 >> 12;             // NA = 4096
    const int tid = threadIdx.x;
    const int wave = tid >> 6, lane = tid & 63;
    const int l15 = lane & 15, quad = lane >> 4;

    __shared__ __align__(16) char u_region[32 * 392 * 2]; // Ms | geo alias
    __shared__ unsigned short Ys[32][136];                // 8704 B
    __shared__ float Rs[32][9];
    __shared__ float cen[32][3];
    __shared__ float mk[32];

    unsigned short (*Ms)[392]   = (unsigned short(*)[392])u_region;
    float4        (*rel4)[K_]    = (float4(*)[K_])u_region;                 // 8192 B
    unsigned int  (*anbP)[K_][6] = (unsigned int(*)[K_][6])(u_region + 8192); // 12288 B

    // ---- phase A: frames + masks (threads 0..31) ----
    if (tid < 32) {
        const int atom = a0 + tid;
        const int fb = atom * 3;
        const int i0 = frame_idx[fb + 0];
        const int i1 = frame_idx[fb + 1];
        const int i2 = frame_idx[fb + 2];
        const float* pcb = pc + (size_t)b * NPC_ * 3;
        float p0x = pcb[i0*3+0], p0y = pcb[i0*3+1], p0z = pcb[i0*3+2];
        float cx  = pcb[i1*3+0], cy  = pcb[i1*3+1], cz  = pcb[i1*3+2];
        float p2x = pcb[i2*3+0], p2y = pcb[i2*3+1], p2z = pcb[i2*3+2];
        float u1x = p2x - cx, u1y = p2y - cy, u1z = p2z - cz;
        float n1 = sqrtf(u1x*u1x + u1y*u1y + u1z*u1z) + 1e-8f;
        u1x /= n1; u1y /= n1; u1z /= n1;
        float vx = p0x - cx, vy = p0y - cy, vz = p0z - cz;
        float dot = vx*u1x + vy*u1y + vz*u1z;
        float u2x = vx - dot*u1x, u2y = vy - dot*u1y, u2z = vz - dot*u1z;
        float n2 = sqrtf(u2x*u2x + u2y*u2y + u2z*u2z) + 1e-8f;
        u2x /= n2; u2y /= n2; u2z /= n2;
        float u3x = u1y*u2z - u1z*u2y;
        float u3y = u1z*u2x - u1x*u2z;
        float u3z = u1x*u2y - u1y*u2x;
        Rs[tid][0]=u1x; Rs[tid][1]=u1y; Rs[tid][2]=u1z;
        Rs[tid][3]=u2x; Rs[tid][4]=u2y; Rs[tid][5]=u2z;
        Rs[tid][6]=u3x; Rs[tid][7]=u3y; Rs[tid][8]=u3z;
        cen[tid][0]=cx; cen[tid][1]=cy; cen[tid][2]=cz;
        const int ai = attr_idx[atom];
        float m = 0.f;
        #pragma unroll
        for (int a = 0; a < DA_; a++)
            if (attr_table[ai*DA_ + a] != 0.f) m = 1.f;
        const float mv = mask_atom[atom] * m;
        mk[tid] = mv;
        mask_y[atom] = mv;
    }
    __syncthreads();

    // ---- phase B: rel coords + packed neighbor attrs (512 tasks, 2 iters) --
    #pragma unroll
    for (int it = 0; it < 2; it++) {
        const int idx = tid + it * 256;          // < 512
        const int t = idx >> 4, k = idx & 15;
        const int j  = nb_idx[(a0 + t) * K_ + k];
        const int ai = attr_idx[b * NA_ + j];
        const int fj = frame_idx[(b * NA_ + j) * 3 + 1];
        const float* pcb = pc + (size_t)b * NPC_ * 3;
        float dx = pcb[fj*3+0] - cen[t][0];
        float dy = pcb[fj*3+1] - cen[t][1];
        float dz = pcb[fj*3+2] - cen[t][2];
        float4 r;
        r.x = Rs[t][0]*dx + Rs[t][1]*dy + Rs[t][2]*dz;
        r.y = Rs[t][3]*dx + Rs[t][4]*dy + Rs[t][5]*dz;
        r.z = Rs[t][6]*dx + Rs[t][7]*dy + Rs[t][8]*dz;
        r.w = 0.f;
        rel4[t][k] = r;
        const float4* src = (const float4*)attr_table + (size_t)ai * 3;
        #pragma unroll
        for (int q = 0; q < 3; q++) {
            const float4 v = src[q];
            anbP[t][k][q*2]   = (unsigned int)f2bf(v.x) | ((unsigned int)f2bf(v.y) << 16);
            anbP[t][k][q*2+1] = (unsigned int)f2bf(v.z) | ((unsigned int)f2bf(v.w) << 16);
        }
    }
    __syncthreads();

    // ---- phase C: contraction into REGISTERS (geo region stays readable) ---
    float accR[4][DA_];
    #pragma unroll
    for (int it = 0; it < 4; it++) {
        const int idx = tid + it * 256;          // < 1024
        const int t = idx >> 5, g = idx & 31;
        const float gx = gauss[g*3+0], gy = gauss[g*3+1], gz = gauss[g*3+2];
        float* acc = accR[it];
        #pragma unroll
        for (int a = 0; a < DA_; a++) acc[a] = 0.f;
        #pragma unroll
        for (int k = 0; k < K_; k++) {
            const float4 r = rel4[t][k];
            const float dx = r.x - gx, dy = r.y - gy, dz = r.z - gz;
            const float gv = __expf(-0.5f * (dx*dx + dy*dy + dz*dz));
            #pragma unroll
            for (int q = 0; q < 6; q++) {
                const unsigned int u = anbP[t][k][q];
                acc[2*q]   += gv * bflo(u);
                acc[2*q+1] += gv * bfhi(u);
            }
        }
    }
    __syncthreads();   // all geo reads done; Ms may now overwrite the region

    #pragma unroll
    for (int it = 0; it < 4; it++) {
        const int idx = tid + it * 256;
        const int t = idx >> 5, g = idx & 31;
        unsigned int* dst = (unsigned int*)&Ms[t][g * 12];
        const float* acc = accR[it];
        #pragma unroll
        for (int i = 0; i < 6; i++) {
            const unsigned int lo = f2bf(acc[2*i]);
            const unsigned int hi = f2bf(acc[2*i+1]);
            dst[i] = lo | (hi << 16);
        }
    }
    __syncthreads();

    // ---- stage 1: Y = (M @ WnT^T) * mask/16, into Ys ----
    const int n0 = wave * 32;
    const unsigned short* bp0 = WnT + (size_t)(n0 + l15) * 384 + quad * 8;
    const unsigned short* bp1 = bp0 + (size_t)16 * 384;

    floatx4 c00 = {0.f,0.f,0.f,0.f}, c01 = {0.f,0.f,0.f,0.f};
    floatx4 c10 = {0.f,0.f,0.f,0.f}, c11 = {0.f,0.f,0.f,0.f};
    #pragma unroll
    for (int k0 = 0; k0 < 384; k0 += 32) {
        short8 a0v = *reinterpret_cast<const short8*>(&Ms[l15][quad * 8 + k0]);
        short8 a1v = *reinterpret_cast<const short8*>(&Ms[16 + l15][quad * 8 + k0]);
        short8 b0 = *reinterpret_cast<const short8*>(bp0 + k0);
        short8 b1 = *reinterpret_cast<const short8*>(bp1 + k0);
        c00 = __builtin_amdgcn_mfma_f32_16x16x32_bf16(a0v, b0, c00, 0, 0, 0);
        c01 = __builtin_amdgcn_mfma_f32_16x16x32_bf16(a0v, b1, c01, 0, 0, 0);
        c10 = __builtin_amdgcn_mfma_f32_16x16x32_bf16(a1v, b0, c10, 0, 0, 0);
        c11 = __builtin_amdgcn_mfma_f32_16x16x32_bf16(a1v, b1, c11, 0, 0, 0);
    }
    #pragma unroll
    for (int r = 0; r < 4; r++) {
        const int r0 = quad * 4 + r;
        const float s0 = mk[r0]      * (1.f / 16.f);
        const float s1 = mk[16 + r0] * (1.f / 16.f);
        Ys[r0][n0 + l15]           = f2bf(c00[r] * s0);
        Ys[r0][n0 + 16 + l15]      = f2bf(c01[r] * s0);
        Ys[16 + r0][n0 + l15]      = f2bf(c10[r] * s1);
        Ys[16 + r0][n0 + 16 + l15] = f2bf(c11[r] * s1);
    }
    __syncthreads();

    // ---- stage 2: AF = (Y @ W2T^T) * mask ----
    const int c0 = wave * 64;
    const unsigned short* bq = W2T + (size_t)(c0 + l15) * F_ + quad * 8;

    floatx4 f0[4], f1[4];
    #pragma unroll
    for (int t = 0; t < 4; t++) {
        f0[t] = (floatx4){0.f,0.f,0.f,0.f};
        f1[t] = (floatx4){0.f,0.f,0.f,0.f};
    }
    #pragma unroll
    for (int k0 = 0; k0 < 128; k0 += 32) {
        short8 a0v = *reinterpret_cast<const short8*>(&Ys[l15][k0 + quad * 8]);
        short8 a1v = *reinterpret_cast<const short8*>(&Ys[16 + l15][k0 + quad * 8]);
        #pragma unroll
        for (int t = 0; t < 4; t++) {
            short8 bv = *reinterpret_cast<const short8*>(bq + (size_t)t * 16 * F_ + k0);
            f0[t] = __builtin_amdgcn_mfma_f32_16x16x32_bf16(a0v, bv, f0[t], 0, 0, 0);
            f1[t] = __builtin_amdgcn_mfma_f32_16x16x32_bf16(a1v, bv, f1[t], 0, 0, 0);
        }
    }
    #pragma unroll
    for (int r = 0; r < 4; r++) {
        const int r0 = quad * 4 + r;
        const float s0 = mk[r0], s1 = mk[16 + r0];
        unsigned short* o0 = AF + (size_t)(a0 + r0) * 256 + c0 + l15;
        unsigned short* o1 = AF + (size_t)(a0 + 16 + r0) * 256 + c0 + l15;
        #pragma unroll
        for (int t = 0; t < 4; t++) {
            o0[t * 16] = f2bf(f0[t][r] * s0);
            o1[t * 16] = f2bf(f1[t][r] * s1);
        }
    }
}

// ---------------------------------------------------------------------------
// k_pool_stats: masked/gated softmax pooling (16 rows/block) + fused stats.
// 256 threads: rl = tid>>7 handles rows {rl, rl+2, ..., rl+14}.
// ---------------------------------------------------------------------------
__global__ __launch_bounds__(256) void k_pool_stats(
    const unsigned short* __restrict__ AF,
    const float* __restrict__ mask_y,
    const float* __restrict__ mask_aa,     // (B,NAA)
    const int* __restrict__ seq_idx_atom,  // (B,NA)
    const int* __restrict__ seq_idx_aa,    // (B,NAA)
    const int* __restrict__ aa_nb_idx,     // (B,NAA,14)
    float* __restrict__ pooled,
    float* __restrict__ stats)             // S1[128],S2[128],n
{
    const int tid  = threadIdx.x;
    const int rl   = tid >> 7;             // 0..1
    const int f    = tid & 127;
    const int row0 = blockIdx.x * 16;

    __shared__ float gateS[16][KNC_], maskS[16][KNC_];
    __shared__ int   jS[16][KNC_];
    __shared__ float red[128];

    if (tid < 16 * KNC_) {
        const int r = tid / KNC_, k = tid % KNC_;
        const int rr = row0 + r;
        const int bb = rr >> 10;
        const int j = aa_nb_idx[rr * KNC_ + k];
        jS[r][k] = j;
        maskS[r][k] = mask_y[bb * NA_ + j];
        const int sa = seq_idx_aa[rr];
        const int sn = seq_idx_atom[bb * NA_ + j];
        gateS[r][k] = (sn == sa) ? 1.f : 0.f;
    }
    __syncthreads();

    float s1 = 0.f, s2 = 0.f;
    #pragma unroll
    for (int it = 0; it < 8; it++) {
        const int r   = it * 2 + rl;
        const int row = row0 + r;
        const int bb  = row >> 10;

        float av[KNC_], fv[KNC_];
        #pragma unroll
        for (int k = 0; k < KNC_; k++) {
            const size_t o = ((size_t)(bb * NA_ + jS[r][k])) * 256 + f;
            av[k] = bf2f(AF[o]);
            fv[k] = bf2f(AF[o + 128]);
        }
        float m = -1e30f;
        #pragma unroll
        for (int k = 0; k < KNC_; k++) {
            const float l = (maskS[r][k] > 0.f) ? av[k] : -1e9f;
            av[k] = l;
            m = fmaxf(m, l);
        }
        float s = 0.f;
        #pragma unroll
        for (int k = 0; k < KNC_; k++) { av[k] = __expf(av[k] - m); s += av[k]; }
        float tot = 0.f, p = 0.f;
        #pragma unroll
        for (int k = 0; k < KNC_; k++) {
            const float w = av[k] / s * gateS[r][k] * maskS[r][k];
            tot += w;
            p   += w * fv[k];
        }
        p = p / (tot + 1e-8f);
        p *= mask_aa[row];
        pooled[(size_t)row * F_ + f] = p;
        s1 += p;
        s2 += p * p;
    }

    // block-level reduce then one atomic per feature per stat
    if (rl == 1) red[f] = s1;
    __syncthreads();
    if (rl == 0) atomicAdd(&stats[f], s1 + red[f]);
    __syncthreads();
    if (rl == 1) red[f] = s2;
    __syncthreads();
    if (rl == 0) atomicAdd(&stats[F_ + f], s2 + red[f]);
    if (tid == 0) {
        float n = 0.f;
        #pragma unroll
        for (int r = 0; r < 16; r++) n += mask_aa[row0 + r];
        atomicAdd(&stats[2 * F_], n);
    }
}

// ---------------------------------------------------------------------------
// k_final: batchnorm + relu + store; echo mask_aa as output 1
// ---------------------------------------------------------------------------
__global__ __launch_bounds__(256) void k_final(
    const float* __restrict__ pooled,
    const float* __restrict__ stats,
    const float* __restrict__ gamma,
    const float* __restrict__ beta,
    const float* __restrict__ mask_aa,
    float* __restrict__ out)
{
    const int idx = blockIdx.x * 256 + threadIdx.x;   // < B*NAA*D
    const int f   = idx & (D_ - 1);
    const int row = idx >> 7;
    const float n    = stats[2 * F_] + 1e-8f;
    const float mean = stats[f] / n;
    const float var  = stats[F_ + f] / n - mean * mean;
    const float ma   = mask_aa[row];
    float v = gamma[f] * (pooled[idx] - mean) * rsqrtf(var + 1e-5f) + beta[f];
    v = fmaxf(v * ma, 0.f);
    out[idx] = v;
    if (idx < B_ * NAA_) out[B_ * NAA_ * D_ + idx] = mask_aa[idx];
}

// ---------------------------------------------------------------------------
extern "C" void kernel_launch(void* const* d_in, const int* in_sizes, int n_in,
                              void* d_out, int out_size, void* d_ws, size_t ws_size,
                              hipStream_t stream) {
    const float* pc         = (const float*)d_in[0];
    const float* mask_atom  = (const float*)d_in[1];
    const float* mask_aa    = (const float*)d_in[2];
    const float* attr_table = (const float*)d_in[3];
    const float* gauss      = (const float*)d_in[4];
    const float* W_nem      = (const float*)d_in[5];
    const float* W_att      = (const float*)d_in[6];
    const float* W_feat     = (const float*)d_in[7];
    const float* gamma      = (const float*)d_in[8];
    const float* beta       = (const float*)d_in[9];
    const int* frame_idx    = (const int*)d_in[10];
    const int* attr_idx     = (const int*)d_in[11];
    const int* nb_idx       = (const int*)d_in[12];
    const int* seq_idx_atom = (const int*)d_in[13];
    const int* seq_idx_aa   = (const int*)d_in[14];
    const int* aa_nb_idx    = (const int*)d_in[15];

    // Workspace layout (~21.3 MB of the provided ws)
    char* base = (char*)d_ws;
    unsigned short* AF  = (unsigned short*)base;                         // 16777216
    unsigned short* WnT = (unsigned short*)(base + 16777216);            // 98304
    unsigned short* W2T = (unsigned short*)(base + 16777216 + 98304);    // 65536
    float* masky  = (float*)(base + 16777216 + 98304 + 65536);           // 131072
    float* pooled = (float*)(base + 16777216 + 98304 + 65536 + 131072);  // 4194304
    float* stats  = (float*)(base + 16777216 + 98304 + 65536 + 131072 + 4194304);

    k_prep<<<321, 256, 0, stream>>>(W_nem, W_att, W_feat, WnT, W2T, stats);
    k_fused<<<B_*NA_/32, 256, 0, stream>>>(pc, mask_atom, attr_table, gauss,
                                           frame_idx, attr_idx, nb_idx,
                                           WnT, W2T, masky, AF);
    k_pool_stats<<<B_*NAA_/16, 256, 0, stream>>>(AF, masky, mask_aa,
                                                 seq_idx_atom, seq_idx_aa,
                                                 aa_nb_idx, pooled, stats);
    k_final<<<(B_*NAA_*D_) / 256, 256, 0, stream>>>(pooled, stats, gamma, beta,
                                                    mask_aa, (float*)d_out);
}

// Round 9
// 150.194 us; speedup vs baseline: 2.4782x; 1.0068x over previous
//
#include <hip/hip_runtime.h>
#include <hip/hip_bf16.h>

// Problem constants
#define B_    8
#define NA_   4096
#define NAA_  1024
#define NPC_  4096
#define K_    16
#define KNC_  14
#define G_    32
#define DA_   12
#define F_    128
#define D_    128

typedef __attribute__((ext_vector_type(8))) short short8;
typedef __attribute__((ext_vector_type(4))) float floatx4;

__device__ __forceinline__ unsigned short f2bf(float x) {
    __hip_bfloat16 h = __float2bfloat16(x);
    return *reinterpret_cast<unsigned short*>(&h);
}
__device__ __forceinline__ float bf2f(unsigned short u) {
    __hip_bfloat16 h;
    *reinterpret_cast<unsigned short*>(&h) = u;
    return __bfloat162float(h);
}
__device__ __forceinline__ float bflo(unsigned int u) {   // low bf16 of pair
    return __uint_as_float(u << 16);
}
__device__ __forceinline__ float bfhi(unsigned int u) {   // high bf16 of pair
    return __uint_as_float(u & 0xffff0000u);
}

// ---------------------------------------------------------------------------
// k_prep: transpose weights to bf16 + zero stats (block 320).
//   WnT[f][ga] = W_nem[ga][f]          (128 x 384)
//   W2T[n][k]  = n<128 ? W_att[k][n] : W_feat[k][n-128]   (256 x 128)
// ---------------------------------------------------------------------------
__global__ __launch_bounds__(256) void k_prep(
    const float* __restrict__ W_nem, const float* __restrict__ W_att,
    const float* __restrict__ W_feat,
    unsigned short* __restrict__ WnT, unsigned short* __restrict__ W2T,
    float* __restrict__ stats)   // 257 floats: S1[128],S2[128],n
{
    if (blockIdx.x == 320) {
        if (threadIdx.x < 257) stats[threadIdx.x] = 0.f;
        return;
    }
    const int idx = blockIdx.x * 256 + threadIdx.x;   // < 81920
    if (idx < 128 * 384) {
        const int f = idx / 384, ga = idx % 384;
        WnT[idx] = f2bf(W_nem[(size_t)ga * F_ + f]);
    } else if (idx < 128 * 384 + 256 * 128) {
        const int j = idx - 128 * 384;
        const int n = j / 128, k = j % 128;
        const float v = (n < 128) ? W_att[(size_t)k * F_ + n]
                                  : W_feat[(size_t)k * F_ + (n - 128)];
        W2T[j] = f2bf(v);
    }
}

// ---------------------------------------------------------------------------
// k_fused: geometry -> M (LDS) -> Y (LDS) -> AF2 (global), 32 atoms/block.
// AF2[atom][f] = uint32( att bf16 | feat bf16 << 16 ), f in [0,128).
// Stage 2: wave w computes att cols [32w,32w+32) AND feat cols [32w,32w+32)
// so each lane packs its (att,feat) pair into one dword store.
// ---------------------------------------------------------------------------
__global__ __launch_bounds__(256, 4) void k_fused(
    const float* __restrict__ pc,         // (B,NPC,3)
    const float* __restrict__ mask_atom,  // (B,NA)
    const float* __restrict__ attr_table, // (39,12)
    const float* __restrict__ gauss,      // (32,3)
    const int* __restrict__ frame_idx,    // (B,NA,3)
    const int* __restrict__ attr_idx,     // (B,NA)
    const int* __restrict__ nb_idx,       // (B,NA,16)
    const unsigned short* __restrict__ WnT,   // (128,384)
    const unsigned short* __restrict__ W2T,   // (256,128)
    float* __restrict__ mask_y,
    unsigned int* __restrict__ AF2)           // (32768,128) packed
{
    const int a0  = blockIdx.x * 32;      // first atom
    const int b   = a0 >> 12;             // NA = 4096
    const int tid = threadIdx.x;
    const int wave = tid >> 6, lane = tid & 63;
    const int l15 = lane & 15, quad = lane >> 4;

    __shared__ __align__(16) char u_region[32 * 392 * 2]; // Ms | geo alias
    __shared__ unsigned short Ys[32][136];                // 8704 B
    __shared__ float Rs[32][9];
    __shared__ float cen[32][3];
    __shared__ float mk[32];

    unsigned short (*Ms)[392]    = (unsigned short(*)[392])u_region;
    float4        (*rel4)[K_]    = (float4(*)[K_])u_region;                   // 8192 B
    unsigned int  (*anbP)[K_][6] = (unsigned int(*)[K_][6])(u_region + 8192); // 12288 B

    // ---- phase A: frames + masks (threads 0..31) ----
    if (tid < 32) {
        const int atom = a0 + tid;
        const int fb = atom * 3;
        const int i0 = frame_idx[fb + 0];
        const int i1 = frame_idx[fb + 1];
        const int i2 = frame_idx[fb + 2];
        const float* pcb = pc + (size_t)b * NPC_ * 3;
        float p0x = pcb[i0*3+0], p0y = pcb[i0*3+1], p0z = pcb[i0*3+2];
        float cx  = pcb[i1*3+0], cy  = pcb[i1*3+1], cz  = pcb[i1*3+2];
        float p2x = pcb[i2*3+0], p2y = pcb[i2*3+1], p2z = pcb[i2*3+2];
        float u1x = p2x - cx, u1y = p2y - cy, u1z = p2z - cz;
        float n1 = sqrtf(u1x*u1x + u1y*u1y + u1z*u1z) + 1e-8f;
        u1x /= n1; u1y /= n1; u1z /= n1;
        float vx = p0x - cx, vy = p0y - cy, vz = p0z - cz;
        float dot = vx*u1x + vy*u1y + vz*u1z;
        float u2x = vx - dot*u1x, u2y = vy - dot*u1y, u2z = vz - dot*u1z;
        float n2 = sqrtf(u2x*u2x + u2y*u2y + u2z*u2z) + 1e-8f;
        u2x /= n2; u2y /= n2; u2z /= n2;
        float u3x = u1y*u2z - u1z*u2y;
        float u3y = u1z*u2x - u1x*u2z;
        float u3z = u1x*u2y - u1y*u2x;
        Rs[tid][0]=u1x; Rs[tid][1]=u1y; Rs[tid][2]=u1z;
        Rs[tid][3]=u2x; Rs[tid][4]=u2y; Rs[tid][5]=u2z;
        Rs[tid][6]=u3x; Rs[tid][7]=u3y; Rs[tid][8]=u3z;
        cen[tid][0]=cx; cen[tid][1]=cy; cen[tid][2]=cz;
        const int ai = attr_idx[atom];
        float m = 0.f;
        #pragma unroll
        for (int a = 0; a < DA_; a++)
            if (attr_table[ai*DA_ + a] != 0.f) m = 1.f;
        const float mv = mask_atom[atom] * m;
        mk[tid] = mv;
        mask_y[atom] = mv;
    }
    __syncthreads();

    // ---- phase B: rel coords + packed neighbor attrs (512 tasks, 2 iters) --
    #pragma unroll
    for (int it = 0; it < 2; it++) {
        const int idx = tid + it * 256;          // < 512
        const int t = idx >> 4, k = idx & 15;
        const int j  = nb_idx[(a0 + t) * K_ + k];
        const int ai = attr_idx[b * NA_ + j];
        const int fj = frame_idx[(b * NA_ + j) * 3 + 1];
        const float* pcb = pc + (size_t)b * NPC_ * 3;
        float dx = pcb[fj*3+0] - cen[t][0];
        float dy = pcb[fj*3+1] - cen[t][1];
        float dz = pcb[fj*3+2] - cen[t][2];
        float4 r;
        r.x = Rs[t][0]*dx + Rs[t][1]*dy + Rs[t][2]*dz;
        r.y = Rs[t][3]*dx + Rs[t][4]*dy + Rs[t][5]*dz;
        r.z = Rs[t][6]*dx + Rs[t][7]*dy + Rs[t][8]*dz;
        r.w = 0.f;
        rel4[t][k] = r;
        const float4* src = (const float4*)attr_table + (size_t)ai * 3;
        #pragma unroll
        for (int q = 0; q < 3; q++) {
            const float4 v = src[q];
            anbP[t][k][q*2]   = (unsigned int)f2bf(v.x) | ((unsigned int)f2bf(v.y) << 16);
            anbP[t][k][q*2+1] = (unsigned int)f2bf(v.z) | ((unsigned int)f2bf(v.w) << 16);
        }
    }
    __syncthreads();

    // ---- phase C: contraction into REGISTERS (geo region stays readable) ---
    float accR[4][DA_];
    #pragma unroll
    for (int it = 0; it < 4; it++) {
        const int idx = tid + it * 256;          // < 1024
        const int t = idx >> 5, g = idx & 31;
        const float gx = gauss[g*3+0], gy = gauss[g*3+1], gz = gauss[g*3+2];
        float* acc = accR[it];
        #pragma unroll
        for (int a = 0; a < DA_; a++) acc[a] = 0.f;
        #pragma unroll
        for (int k = 0; k < K_; k++) {
            const float4 r = rel4[t][k];
            const float dx = r.x - gx, dy = r.y - gy, dz = r.z - gz;
            const float gv = __expf(-0.5f * (dx*dx + dy*dy + dz*dz));
            #pragma unroll
            for (int q = 0; q < 6; q++) {
                const unsigned int u = anbP[t][k][q];
                acc[2*q]   += gv * bflo(u);
                acc[2*q+1] += gv * bfhi(u);
            }
        }
    }
    __syncthreads();   // all geo reads done; Ms may now overwrite the region

    #pragma unroll
    for (int it = 0; it < 4; it++) {
        const int idx = tid + it * 256;
        const int t = idx >> 5, g = idx & 31;
        unsigned int* dst = (unsigned int*)&Ms[t][g * 12];
        const float* acc = accR[it];
        #pragma unroll
        for (int i = 0; i < 6; i++) {
            const unsigned int lo = f2bf(acc[2*i]);
            const unsigned int hi = f2bf(acc[2*i+1]);
            dst[i] = lo | (hi << 16);
        }
    }
    __syncthreads();

    // ---- stage 1: Y = (M @ WnT^T) * mask/16, into Ys ----
    const int n0 = wave * 32;
    const unsigned short* bp0 = WnT + (size_t)(n0 + l15) * 384 + quad * 8;
    const unsigned short* bp1 = bp0 + (size_t)16 * 384;

    floatx4 c00 = {0.f,0.f,0.f,0.f}, c01 = {0.f,0.f,0.f,0.f};
    floatx4 c10 = {0.f,0.f,0.f,0.f}, c11 = {0.f,0.f,0.f,0.f};
    #pragma unroll
    for (int k0 = 0; k0 < 384; k0 += 32) {
        short8 a0v = *reinterpret_cast<const short8*>(&Ms[l15][quad * 8 + k0]);
        short8 a1v = *reinterpret_cast<const short8*>(&Ms[16 + l15][quad * 8 + k0]);
        short8 b0 = *reinterpret_cast<const short8*>(bp0 + k0);
        short8 b1 = *reinterpret_cast<const short8*>(bp1 + k0);
        c00 = __builtin_amdgcn_mfma_f32_16x16x32_bf16(a0v, b0, c00, 0, 0, 0);
        c01 = __builtin_amdgcn_mfma_f32_16x16x32_bf16(a0v, b1, c01, 0, 0, 0);
        c10 = __builtin_amdgcn_mfma_f32_16x16x32_bf16(a1v, b0, c10, 0, 0, 0);
        c11 = __builtin_amdgcn_mfma_f32_16x16x32_bf16(a1v, b1, c11, 0, 0, 0);
    }
    #pragma unroll
    for (int r = 0; r < 4; r++) {
        const int r0 = quad * 4 + r;
        const float s0 = mk[r0]      * (1.f / 16.f);
        const float s1 = mk[16 + r0] * (1.f / 16.f);
        Ys[r0][n0 + l15]           = f2bf(c00[r] * s0);
        Ys[r0][n0 + 16 + l15]      = f2bf(c01[r] * s0);
        Ys[16 + r0][n0 + l15]      = f2bf(c10[r] * s1);
        Ys[16 + r0][n0 + 16 + l15] = f2bf(c11[r] * s1);
    }
    __syncthreads();

    // ---- stage 2: att cols [32w,32w+32) + feat cols [32w,32w+32) ----
    // tiles t: 0,1 -> att (W2T rows 32w+16t); 2,3 -> feat (W2T rows 128+32w+16(t-2))
    const int cw = wave * 32;

    floatx4 f0[4], f1[4];
    #pragma unroll
    for (int t = 0; t < 4; t++) {
        f0[t] = (floatx4){0.f,0.f,0.f,0.f};
        f1[t] = (floatx4){0.f,0.f,0.f,0.f};
    }
    const unsigned short* bq[4];
    #pragma unroll
    for (int t = 0; t < 4; t++) {
        const int nrow = (t < 2) ? (cw + 16 * t + l15)
                                 : (128 + cw + 16 * (t - 2) + l15);
        bq[t] = W2T + (size_t)nrow * F_ + quad * 8;
    }
    #pragma unroll
    for (int k0 = 0; k0 < 128; k0 += 32) {
        short8 a0v = *reinterpret_cast<const short8*>(&Ys[l15][k0 + quad * 8]);
        short8 a1v = *reinterpret_cast<const short8*>(&Ys[16 + l15][k0 + quad * 8]);
        #pragma unroll
        for (int t = 0; t < 4; t++) {
            short8 bv = *reinterpret_cast<const short8*>(bq[t] + k0);
            f0[t] = __builtin_amdgcn_mfma_f32_16x16x32_bf16(a0v, bv, f0[t], 0, 0, 0);
            f1[t] = __builtin_amdgcn_mfma_f32_16x16x32_bf16(a1v, bv, f1[t], 0, 0, 0);
        }
    }
    #pragma unroll
    for (int r = 0; r < 4; r++) {
        const int r0 = quad * 4 + r;
        const float s0 = mk[r0], s1 = mk[16 + r0];
        unsigned int* o0 = AF2 + (size_t)(a0 + r0) * F_ + cw + l15;
        unsigned int* o1 = AF2 + (size_t)(a0 + 16 + r0) * F_ + cw + l15;
        #pragma unroll
        for (int tp = 0; tp < 2; tp++) {
            const unsigned int p0 = (unsigned int)f2bf(f0[tp][r] * s0)
                                  | ((unsigned int)f2bf(f0[tp + 2][r] * s0) << 16);
            const unsigned int p1 = (unsigned int)f2bf(f1[tp][r] * s1)
                                  | ((unsigned int)f2bf(f1[tp + 2][r] * s1) << 16);
            o0[tp * 16] = p0;
            o1[tp * 16] = p1;
        }
    }
}

// ---------------------------------------------------------------------------
// k_pool_stats: masked/gated softmax pooling (16 rows/block) + fused stats.
// Reads packed AF2: one dword gather per neighbor -> (att, feat).
// ---------------------------------------------------------------------------
__global__ __launch_bounds__(256) void k_pool_stats(
    const unsigned int* __restrict__ AF2,
    const float* __restrict__ mask_y,
    const float* __restrict__ mask_aa,     // (B,NAA)
    const int* __restrict__ seq_idx_atom,  // (B,NA)
    const int* __restrict__ seq_idx_aa,    // (B,NAA)
    const int* __restrict__ aa_nb_idx,     // (B,NAA,14)
    float* __restrict__ pooled,
    float* __restrict__ stats)             // S1[128],S2[128],n
{
    const int tid  = threadIdx.x;
    const int rl   = tid >> 7;             // 0..1
    const int f    = tid & 127;
    const int row0 = blockIdx.x * 16;

    __shared__ float gateS[16][KNC_], maskS[16][KNC_];
    __shared__ int   jS[16][KNC_];
    __shared__ float red[128];

    if (tid < 16 * KNC_) {
        const int r = tid / KNC_, k = tid % KNC_;
        const int rr = row0 + r;
        const int bb = rr >> 10;
        const int j = aa_nb_idx[rr * KNC_ + k];
        jS[r][k] = j;
        maskS[r][k] = mask_y[bb * NA_ + j];
        const int sa = seq_idx_aa[rr];
        const int sn = seq_idx_atom[bb * NA_ + j];
        gateS[r][k] = (sn == sa) ? 1.f : 0.f;
    }
    __syncthreads();

    float s1 = 0.f, s2 = 0.f;
    #pragma unroll
    for (int it = 0; it < 8; it++) {
        const int r   = it * 2 + rl;
        const int row = row0 + r;
        const int bb  = row >> 10;

        float av[KNC_], fv[KNC_];
        #pragma unroll
        for (int k = 0; k < KNC_; k++) {
            const unsigned int u = AF2[((size_t)(bb * NA_ + jS[r][k])) * F_ + f];
            av[k] = bflo(u);
            fv[k] = bfhi(u);
        }
        float m = -1e30f;
        #pragma unroll
        for (int k = 0; k < KNC_; k++) {
            const float l = (maskS[r][k] > 0.f) ? av[k] : -1e9f;
            av[k] = l;
            m = fmaxf(m, l);
        }
        float s = 0.f;
        #pragma unroll
        for (int k = 0; k < KNC_; k++) { av[k] = __expf(av[k] - m); s += av[k]; }
        float tot = 0.f, p = 0.f;
        #pragma unroll
        for (int k = 0; k < KNC_; k++) {
            const float w = av[k] / s * gateS[r][k] * maskS[r][k];
            tot += w;
            p   += w * fv[k];
        }
        p = p / (tot + 1e-8f);
        p *= mask_aa[row];
        pooled[(size_t)row * F_ + f] = p;
        s1 += p;
        s2 += p * p;
    }

    // block-level reduce then one atomic per feature per stat
    if (rl == 1) red[f] = s1;
    __syncthreads();
    if (rl == 0) atomicAdd(&stats[f], s1 + red[f]);
    __syncthreads();
    if (rl == 1) red[f] = s2;
    __syncthreads();
    if (rl == 0) atomicAdd(&stats[F_ + f], s2 + red[f]);
    if (tid == 0) {
        float n = 0.f;
        #pragma unroll
        for (int r = 0; r < 16; r++) n += mask_aa[row0 + r];
        atomicAdd(&stats[2 * F_], n);
    }
}

// ---------------------------------------------------------------------------
// k_final: batchnorm + relu + store; echo mask_aa as output 1
// ---------------------------------------------------------------------------
__global__ __launch_bounds__(256) void k_final(
    const float* __restrict__ pooled,
    const float* __restrict__ stats,
    const float* __restrict__ gamma,
    const float* __restrict__ beta,
    const float* __restrict__ mask_aa,
    float* __restrict__ out)
{
    const int idx = blockIdx.x * 256 + threadIdx.x;   // < B*NAA*D
    const int f   = idx & (D_ - 1);
    const int row = idx >> 7;
    const float n    = stats[2 * F_] + 1e-8f;
    const float mean = stats[f] / n;
    const float var  = stats[F_ + f] / n - mean * mean;
    const float ma   = mask_aa[row];
    float v = gamma[f] * (pooled[idx] - mean) * rsqrtf(var + 1e-5f) + beta[f];
    v = fmaxf(v * ma, 0.f);
    out[idx] = v;
    if (idx < B_ * NAA_) out[B_ * NAA_ * D_ + idx] = mask_aa[idx];
}

// ---------------------------------------------------------------------------
extern "C" void kernel_launch(void* const* d_in, const int* in_sizes, int n_in,
                              void* d_out, int out_size, void* d_ws, size_t ws_size,
                              hipStream_t stream) {
    const float* pc         = (const float*)d_in[0];
    const float* mask_atom  = (const float*)d_in[1];
    const float* mask_aa    = (const float*)d_in[2];
    const float* attr_table = (const float*)d_in[3];
    const float* gauss      = (const float*)d_in[4];
    const float* W_nem      = (const float*)d_in[5];
    const float* W_att      = (const float*)d_in[6];
    const float* W_feat     = (const float*)d_in[7];
    const float* gamma      = (const float*)d_in[8];
    const float* beta       = (const float*)d_in[9];
    const int* frame_idx    = (const int*)d_in[10];
    const int* attr_idx     = (const int*)d_in[11];
    const int* nb_idx       = (const int*)d_in[12];
    const int* seq_idx_atom = (const int*)d_in[13];
    const int* seq_idx_aa   = (const int*)d_in[14];
    const int* aa_nb_idx    = (const int*)d_in[15];

    // Workspace layout (~21.3 MB of the provided ws)
    char* base = (char*)d_ws;
    unsigned int*   AF2 = (unsigned int*)base;                           // 16777216
    unsigned short* WnT = (unsigned short*)(base + 16777216);            // 98304
    unsigned short* W2T = (unsigned short*)(base + 16777216 + 98304);    // 65536
    float* masky  = (float*)(base + 16777216 + 98304 + 65536);           // 131072
    float* pooled = (float*)(base + 16777216 + 98304 + 65536 + 131072);  // 4194304
    float* stats  = (float*)(base + 16777216 + 98304 + 65536 + 131072 + 4194304);

    k_prep<<<321, 256, 0, stream>>>(W_nem, W_att, W_feat, WnT, W2T, stats);
    k_fused<<<B_*NA_/32, 256, 0, stream>>>(pc, mask_atom, attr_table, gauss,
                                           frame_idx, attr_idx, nb_idx,
                                           WnT, W2T, masky, AF2);
    k_pool_stats<<<B_*NAA_/16, 256, 0, stream>>>(AF2, masky, mask_aa,
                                                 seq_idx_atom, seq_idx_aa,
                                                 aa_nb_idx, pooled, stats);
    k_final<<<(B_*NAA_*D_) / 256, 256, 0, stream>>>(pooled, stats, gamma, beta,
                                                    mask_aa, (float*)d_out);
}